// Round 1
// baseline (132.463 us; speedup 1.0000x reference)
//
#include <hip/hip_runtime.h>
#include <math.h>

#define NSAMP 16384
#define ND    512

__device__ __forceinline__ float shxor(float v, int m) { return __shfl_xor(v, m, 64); }

// ---------- gates on local (in-register) wires; LB = local bit ----------
template<int LB>
__device__ __forceinline__ void ry_local(float* sr, float* si, float c, float s) {
#pragma unroll
  for (int r0 = 0; r0 < 8; ++r0) {
    if (r0 & (1 << LB)) continue;
    const int r1 = r0 | (1 << LB);
    float a0r = sr[r0], a0i = si[r0], a1r = sr[r1], a1i = si[r1];
    sr[r0] = c * a0r - s * a1r;  si[r0] = c * a0i - s * a1i;
    sr[r1] = s * a0r + c * a1r;  si[r1] = s * a0i + c * a1i;
  }
}

template<int LB>
__device__ __forceinline__ void rz_local(float* sr, float* si, float c, float s) {
#pragma unroll
  for (int r = 0; r < 8; ++r) {
    const float sg = (r & (1 << LB)) ? s : -s;   // compile-time sign
    float re = sr[r], im = si[r];
    sr[r] = c * re - sg * im;
    si[r] = c * im + sg * re;
  }
}

// ---------- gates on lane-bit wires ----------
__device__ __forceinline__ void ry_lane(float* sr, float* si, float c, float s, int mask, int lane) {
  const float se = (lane & mask) ? s : -s;
#pragma unroll
  for (int r = 0; r < 8; ++r) {
    float pr = shxor(sr[r], mask);
    float pi = shxor(si[r], mask);
    sr[r] = c * sr[r] + se * pr;
    si[r] = c * si[r] + se * pi;
  }
}

__device__ __forceinline__ void rz_lane(float* sr, float* si, float c, float s, int mask, int lane) {
  const float sg = (lane & mask) ? s : -s;
#pragma unroll
  for (int r = 0; r < 8; ++r) {
    float re = sr[r], im = si[r];
    sr[r] = c * re - sg * im;
    si[r] = c * im + sg * re;
  }
}

// ---------- CNOTs ----------
// both wires local: compile-time register permutation (free)
template<int CB, int TB>
__device__ __forceinline__ void cnot_ll(float* sr, float* si) {
#pragma unroll
  for (int r0 = 0; r0 < 8; ++r0) {
    if (!(r0 & (1 << CB)) || (r0 & (1 << TB))) continue;
    const int r1 = r0 | (1 << TB);
    float tr = sr[r0], ti = si[r0];
    sr[r0] = sr[r1]; si[r0] = si[r1];
    sr[r1] = tr;     si[r1] = ti;
  }
}
// control local, target lane: exchange the CB=1 half with partner lane (no select)
template<int CB>
__device__ __forceinline__ void cnot_lt(float* sr, float* si, int tmask) {
#pragma unroll
  for (int r = 0; r < 8; ++r) {
    if (!(r & (1 << CB))) continue;
    sr[r] = shxor(sr[r], tmask);
    si[r] = shxor(si[r], tmask);
  }
}
// control lane, target lane
__device__ __forceinline__ void cnot_tt(float* sr, float* si, int cmask, int tmask, int lane) {
  const bool cc = (lane & cmask) != 0;
#pragma unroll
  for (int r = 0; r < 8; ++r) {
    float pr = shxor(sr[r], tmask);
    float pi = shxor(si[r], tmask);
    sr[r] = cc ? pr : sr[r];
    si[r] = cc ? pi : si[r];
  }
}
// control lane, target local
template<int TB>
__device__ __forceinline__ void cnot_tl(float* sr, float* si, int cmask, int lane) {
  const bool cc = (lane & cmask) != 0;
#pragma unroll
  for (int r0 = 0; r0 < 8; ++r0) {
    if (r0 & (1 << TB)) continue;
    const int r1 = r0 | (1 << TB);
    float n0r = cc ? sr[r1] : sr[r0];
    float n0i = cc ? si[r1] : si[r0];
    float n1r = cc ? sr[r0] : sr[r1];
    float n1i = cc ? si[r0] : si[r1];
    sr[r0] = n0r; si[r0] = n0i;
    sr[r1] = n1r; si[r1] = n1i;
  }
}

__global__ __launch_bounds__(256, 4) void qlayer_kernel(
    const float* __restrict__ x, const float* __restrict__ tstep,
    const float* __restrict__ w_in, const float* __restrict__ b_in,
    const float* __restrict__ g, const float* __restrict__ be,
    const float* __restrict__ qw, const float* __restrict__ w_out,
    const float* __restrict__ b_out, float* __restrict__ out)
{
  __shared__ float s_win[8 * ND];    // w_in  [j][d]
  __shared__ float s_wout[8 * ND];   // w_out transposed: [i][d]
  __shared__ float s_bout[ND];

  const int tid = threadIdx.x;
#pragma unroll
  for (int k = 0; k < 16; ++k) {
    int e = tid + 256 * k;
    s_win[e] = w_in[e];
  }
#pragma unroll
  for (int k = 0; k < 16; ++k) {
    int e = tid + 256 * k;                 // w_out is [d][i], d = e>>3, i = e&7
    s_wout[(e & 7) * ND + (e >> 3)] = w_out[e];
  }
  s_bout[tid]       = b_out[tid];
  s_bout[tid + 256] = b_out[tid + 256];
  __syncthreads();

  const int lane   = tid & 63;
  const int wv     = tid >> 6;
  const int sample = blockIdx.x * 4 + wv;

  // ---------------- input GEMM: h_j = sum_d x[d] * w_in[j][d] ----------------
  const float* xrow = x + (size_t)sample * ND;
  float xv[8];
#pragma unroll
  for (int m = 0; m < 8; ++m) xv[m] = xrow[lane + 64 * m];

  float h[8];
#pragma unroll
  for (int j = 0; j < 8; ++j) h[j] = 0.f;
#pragma unroll
  for (int m = 0; m < 8; ++m) {
#pragma unroll
    for (int j = 0; j < 8; ++j)
      h[j] += xv[m] * s_win[j * ND + lane + 64 * m];
  }
#pragma unroll
  for (int mk = 1; mk < 64; mk <<= 1) {
#pragma unroll
    for (int j = 0; j < 8; ++j) h[j] += shxor(h[j], mk);
  }

  // ---------------- tanh + LayerNorm + timestep -> angles ----------------
#pragma unroll
  for (int j = 0; j < 8; ++j) h[j] = tanhf(h[j] + b_in[j]);
  float mu = 0.f;
#pragma unroll
  for (int j = 0; j < 8; ++j) mu += h[j];
  mu *= 0.125f;
  float var = 0.f;
#pragma unroll
  for (int j = 0; j < 8; ++j) { float d = h[j] - mu; var += d * d; }
  var *= 0.125f;
  const float rstd = rsqrtf(var + 1e-5f);
  const float t0 = tstep[0];
  float ang[8];
#pragma unroll
  for (int j = 0; j < 8; ++j) ang[j] = (h[j] - mu) * rstd * g[j] + be[j] + t0;

  // ---------------- per-qubit state u_i = RZ(w1)RX(w0)RZ(a)RX(a)|0> ----------------
  float u0r[8], u0i[8], u1r[8], u1i[8];
#pragma unroll
  for (int i = 0; i < 8; ++i) {
    float sa, ca; __sincosf(ang[i] * 0.5f, &sa, &ca);
    // after RX(a),RZ(a): v0 = (ca^2, -ca*sa), v1 = (sa^2, -sa*ca)
    float v0r = ca * ca, v0i = -ca * sa;
    float v1r = sa * sa, v1i = -sa * ca;
    float s0, c0; __sincosf(qw[0 * 9 + i] * 0.5f, &s0, &c0);
    // RX(w0): v0' = c0*v0 - i*s0*v1 ; v1' = -i*s0*v0 + c0*v1
    float a0r = c0 * v0r + s0 * v1i;
    float a0i = c0 * v0i - s0 * v1r;
    float a1r = c0 * v1r + s0 * v0i;
    float a1i = c0 * v1i - s0 * v0r;
    float s1, c1; __sincosf(qw[1 * 9 + i] * 0.5f, &s1, &c1);
    // RZ(w1): v0 *= e^{-i w1/2}, v1 *= e^{+i w1/2}
    u0r[i] = c1 * a0r + s1 * a0i;  u0i[i] = c1 * a0i - s1 * a0r;
    u1r[i] = c1 * a1r - s1 * a1i;  u1i[i] = c1 * a1i + s1 * a1r;
  }

  // ---------------- build product state ----------------
  // lane bits 0..5 = wires 3..8 ; local bits 0..2 = wires 0..2 ; ancilla (wire8)=|0>
  float hr, hi;
  {
    int b3 = lane & 1;
    hr = b3 ? u1r[3] : u0r[3];
    hi = b3 ? u1i[3] : u0i[3];
#pragma unroll
    for (int i = 4; i <= 7; ++i) {
      int bit = (lane >> (i - 3)) & 1;
      float br = bit ? u1r[i] : u0r[i];
      float bi = bit ? u1i[i] : u0i[i];
      float nr = hr * br - hi * bi;
      float ni = hr * bi + hi * br;
      hr = nr; hi = ni;
    }
    if (lane & 32) { hr = 0.f; hi = 0.f; }   // ancilla |0>
  }
  float sr[8], si[8];
#pragma unroll
  for (int r = 0; r < 8; ++r) {
    float ar = (r & 1) ? u1r[0] : u0r[0];
    float ai = (r & 1) ? u1i[0] : u0i[0];
    float br = (r & 2) ? u1r[1] : u0r[1];
    float bi = (r & 2) ? u1i[1] : u0i[1];
    float t1r = ar * br - ai * bi, t1i = ar * bi + ai * br;
    float cr = (r & 4) ? u1r[2] : u0r[2];
    float ci = (r & 4) ? u1i[2] : u0i[2];
    float t2r = t1r * cr - t1i * ci, t2i = t1r * ci + t1i * cr;
    sr[r] = t2r * hr - t2i * hi;
    si[r] = t2r * hi + t2i * hr;
  }

  // ---------------- entangling layers l = 1..3 ----------------
#pragma unroll
  for (int l = 1; l < 4; ++l) {
    float gc[9], gs[9];
#pragma unroll
    for (int i = 0; i < 9; ++i) __sincosf(qw[l * 9 + i] * 0.5f, &gs[i], &gc[i]);

    cnot_ll<0, 1>(sr, si);                        // CNOT(0,1)
    ry_local<0>(sr, si, gc[0], gs[0]); rz_local<0>(sr, si, gc[0], gs[0]);
    cnot_ll<1, 2>(sr, si);                        // CNOT(1,2)
    ry_local<1>(sr, si, gc[1], gs[1]); rz_local<1>(sr, si, gc[1], gs[1]);
    cnot_lt<2>(sr, si, 1);                        // CNOT(2,3)
    ry_local<2>(sr, si, gc[2], gs[2]); rz_local<2>(sr, si, gc[2], gs[2]);
    cnot_tt(sr, si, 1, 2, lane);                  // CNOT(3,4)
    ry_lane(sr, si, gc[3], gs[3], 1, lane); rz_lane(sr, si, gc[3], gs[3], 1, lane);
    cnot_tt(sr, si, 2, 4, lane);                  // CNOT(4,5)
    ry_lane(sr, si, gc[4], gs[4], 2, lane); rz_lane(sr, si, gc[4], gs[4], 2, lane);
    cnot_tt(sr, si, 4, 8, lane);                  // CNOT(5,6)
    ry_lane(sr, si, gc[5], gs[5], 4, lane); rz_lane(sr, si, gc[5], gs[5], 4, lane);
    cnot_tt(sr, si, 8, 16, lane);                 // CNOT(6,7)
    ry_lane(sr, si, gc[6], gs[6], 8, lane); rz_lane(sr, si, gc[6], gs[6], 8, lane);
    cnot_tl<0>(sr, si, 16, lane);                 // CNOT(7,0)
    ry_lane(sr, si, gc[7], gs[7], 16, lane); rz_lane(sr, si, gc[7], gs[7], 16, lane);
    cnot_tt(sr, si, 16, 32, lane);                // CNOT(7,8)
    ry_lane(sr, si, gc[8], gs[8], 32, lane);      // RY on ancilla
  }

  // ---------------- Z expectations ----------------
  float p[8];
#pragma unroll
  for (int r = 0; r < 8; ++r) p[r] = sr[r] * sr[r] + si[r] * si[r];
  float tot = 0.f;
#pragma unroll
  for (int r = 0; r < 8; ++r) tot += p[r];

  float z[8];
  z[0] = (p[0] - p[1]) + (p[2] - p[3]) + (p[4] - p[5]) + (p[6] - p[7]);
  z[1] = (p[0] + p[1]) - (p[2] + p[3]) + (p[4] + p[5]) - (p[6] + p[7]);
  z[2] = (p[0] + p[1] + p[2] + p[3]) - (p[4] + p[5] + p[6] + p[7]);
#pragma unroll
  for (int i = 3; i <= 7; ++i) z[i] = (lane & (1 << (i - 3))) ? -tot : tot;
#pragma unroll
  for (int mk = 1; mk < 64; mk <<= 1) {
#pragma unroll
    for (int j = 0; j < 8; ++j) z[j] += shxor(z[j], mk);
  }

  // ---------------- epilogue: out = x + z @ w_out^T + b_out ----------------
  const size_t base = (size_t)sample * ND;
#pragma unroll
  for (int m = 0; m < 8; ++m) {
    const int d = lane + 64 * m;
    float o = xv[m] + s_bout[d];
#pragma unroll
    for (int i = 0; i < 8; ++i) o += z[i] * s_wout[i * ND + d];
    out[base + d] = o;
  }
}

extern "C" void kernel_launch(void* const* d_in, const int* in_sizes, int n_in,
                              void* d_out, int out_size, void* d_ws, size_t ws_size,
                              hipStream_t stream) {
  const float* x     = (const float*)d_in[0];
  const float* ts    = (const float*)d_in[1];
  const float* w_in  = (const float*)d_in[2];
  const float* b_in  = (const float*)d_in[3];
  const float* g     = (const float*)d_in[4];
  const float* be    = (const float*)d_in[5];
  const float* qw    = (const float*)d_in[6];
  const float* w_out = (const float*)d_in[7];
  const float* b_out = (const float*)d_in[8];
  float* out = (float*)d_out;

  qlayer_kernel<<<dim3(NSAMP / 4), dim3(256), 0, stream>>>(
      x, ts, w_in, b_in, g, be, qw, w_out, b_out, out);
}

// Round 3
// 119.662 us; speedup vs baseline: 1.1070x; 1.1070x over previous
//
#include <hip/hip_runtime.h>
#include <math.h>

#define NSAMP 16384
#define ND    512

// ---------------- cross-lane primitives (VALU where possible) ----------------
template<int CTRL>
__device__ __forceinline__ float dppf(float x) {
  return __int_as_float(__builtin_amdgcn_update_dpp(
      __float_as_int(x), __float_as_int(x), CTRL, 0xF, 0xF, true));
}

#if __has_builtin(__builtin_amdgcn_permlane16_swap)
#define HAVE_PLSWAP 1
#endif

// After a permlane16 row-swap of (x,x), at EVERY lane {a,b} == {self, x[lane^16]}
// bitwise, in an order that depends only on row parity. We never assume the
// order: consumers use a+b (sums) or a^b^self (exact partner recovery).
__device__ __forceinline__ void plswap16(float x, float& a, float& b) {
#ifdef HAVE_PLSWAP
  auto r = __builtin_amdgcn_permlane16_swap(__float_as_uint(x), __float_as_uint(x), false, false);
  a = __uint_as_float(r[0]); b = __uint_as_float(r[1]);
#else
  a = x;
  b = __int_as_float(__builtin_amdgcn_ds_swizzle(__float_as_int(x), 0x401F)); // xor16
#endif
}

__device__ __forceinline__ void plswap32(float x, float& a, float& b) {
#ifdef HAVE_PLSWAP
  auto r = __builtin_amdgcn_permlane32_swap(__float_as_uint(x), __float_as_uint(x), false, false);
  a = __uint_as_float(r[0]); b = __uint_as_float(r[1]);
#else
  a = x;
  b = __shfl_xor(x, 32, 64);
#endif
}

// butterfly exchange: return value of lane (lane ^ M)
template<int M>
__device__ __forceinline__ float bfly(float x, int lane) {
  if constexpr (M == 1) {
    return dppf<0xB1>(x);                       // quad_perm [1,0,3,2]
  } else if constexpr (M == 2) {
    return dppf<0x4E>(x);                       // quad_perm [2,3,0,1]
  } else if constexpr (M == 4) {
    return __int_as_float(__builtin_amdgcn_ds_swizzle(__float_as_int(x), 0x101F));
  } else if constexpr (M == 8) {
    return dppf<0x128>(x);                      // row_ror:8 == xor8 within 16
  } else if constexpr (M == 16) {
    float a, b; plswap16(x, a, b);
    return __int_as_float(__float_as_int(a) ^ __float_as_int(b) ^ __float_as_int(x));
  } else {
    float a, b; plswap32(x, a, b);
    return __int_as_float(__float_as_int(a) ^ __float_as_int(b) ^ __float_as_int(x));
  }
}

// full 64-lane sum all-reduce, pure VALU (rotations are fine for sums)
__device__ __forceinline__ float wave_sum(float x) {
  x += dppf<0xB1>(x);                           // xor1
  x += dppf<0x4E>(x);                           // xor2
  x += dppf<0x124>(x);                          // row_ror:4 (sum-valid)
  x += dppf<0x128>(x);                          // row_ror:8
  { float a, b; plswap16(x, a, b); x = a + b; } // row-pair sum
  { float a, b; plswap32(x, a, b); x = a + b; } // half sum
  return x;
}

// ---------------- gates on local (in-register) wires ----------------
template<int LB>
__device__ __forceinline__ void ry_local(float* sr, float* si, float c, float s) {
#pragma unroll
  for (int r0 = 0; r0 < 8; ++r0) {
    if (r0 & (1 << LB)) continue;
    const int r1 = r0 | (1 << LB);
    float a0r = sr[r0], a0i = si[r0], a1r = sr[r1], a1i = si[r1];
    sr[r0] = c * a0r - s * a1r;  si[r0] = c * a0i - s * a1i;
    sr[r1] = s * a0r + c * a1r;  si[r1] = s * a0i + c * a1i;
  }
}

template<int LB>
__device__ __forceinline__ void rz_local(float* sr, float* si, float c, float s) {
#pragma unroll
  for (int r = 0; r < 8; ++r) {
    const float sg = (r & (1 << LB)) ? s : -s;   // compile-time sign
    float re = sr[r], im = si[r];
    sr[r] = c * re - sg * im;
    si[r] = c * im + sg * re;
  }
}

// ---------------- gates on lane-bit wires ----------------
template<int M>
__device__ __forceinline__ void ry_lane(float* sr, float* si, float c, float se, int lane) {
#pragma unroll
  for (int r = 0; r < 8; ++r) {
    float pr = bfly<M>(sr[r], lane);
    float pi = bfly<M>(si[r], lane);
    sr[r] = c * sr[r] + se * pr;
    si[r] = c * si[r] + se * pi;
  }
}

// diagonal: no communication; sg = (lane&mask) ? s : -s precomputed
__device__ __forceinline__ void rz_lane(float* sr, float* si, float c, float sg) {
#pragma unroll
  for (int r = 0; r < 8; ++r) {
    float re = sr[r], im = si[r];
    sr[r] = c * re - sg * im;
    si[r] = c * im + sg * re;
  }
}

// ---------------- CNOTs ----------------
template<int CB, int TB>
__device__ __forceinline__ void cnot_ll(float* sr, float* si) {
#pragma unroll
  for (int r0 = 0; r0 < 8; ++r0) {
    if (!(r0 & (1 << CB)) || (r0 & (1 << TB))) continue;
    const int r1 = r0 | (1 << TB);
    float tr = sr[r0], ti = si[r0];
    sr[r0] = sr[r1]; si[r0] = si[r1];
    sr[r1] = tr;     si[r1] = ti;
  }
}

// control local bit CB, target lane mask TM
template<int CB, int TM>
__device__ __forceinline__ void cnot_lt(float* sr, float* si, int lane) {
#pragma unroll
  for (int r = 0; r < 8; ++r) {
    if (!(r & (1 << CB))) continue;
    sr[r] = bfly<TM>(sr[r], lane);
    si[r] = bfly<TM>(si[r], lane);
  }
}

// control lane mask CM, target lane mask TM
template<int CM, int TM>
__device__ __forceinline__ void cnot_tt(float* sr, float* si, int lane) {
  const bool cc = (lane & CM) != 0;
#pragma unroll
  for (int r = 0; r < 8; ++r) {
    float pr = bfly<TM>(sr[r], lane);
    float pi = bfly<TM>(si[r], lane);
    sr[r] = cc ? pr : sr[r];
    si[r] = cc ? pi : si[r];
  }
}

// control lane mask, target local bit TB
template<int TB>
__device__ __forceinline__ void cnot_tl(float* sr, float* si, int cmask, int lane) {
  const bool cc = (lane & cmask) != 0;
#pragma unroll
  for (int r0 = 0; r0 < 8; ++r0) {
    if (r0 & (1 << TB)) continue;
    const int r1 = r0 | (1 << TB);
    float n0r = cc ? sr[r1] : sr[r0];
    float n0i = cc ? si[r1] : si[r0];
    float n1r = cc ? sr[r0] : sr[r1];
    float n1i = cc ? si[r0] : si[r1];
    sr[r0] = n0r; si[r0] = n0i;
    sr[r1] = n1r; si[r1] = n1i;
  }
}

// Wire->lane-bit map (wires 0,1,2 are register bits 0,1,2):
//   wire4->bit0(m1), wire5->bit1(m2), wire3->bit2(m4), wire6->bit3(m8),
//   wire7->bit4(m16), wire8(ancilla)->bit5(m32)
// mask-4 (the one butterfly with no VALU path) carries the cheapest wire:
// CNOT(2,3) lt (8 swizzles) + RY(3) (16) = 24 LDS ops/layer.

__global__ __launch_bounds__(256, 4) void qlayer_kernel(
    const float* __restrict__ x, const float* __restrict__ tstep,
    const float* __restrict__ w_in, const float* __restrict__ b_in,
    const float* __restrict__ g, const float* __restrict__ be,
    const float* __restrict__ qw, const float* __restrict__ w_out,
    const float* __restrict__ b_out, float* __restrict__ out)
{
  // w_in packed transposed: [j_hi][d][j_lo4] -> conflict-free ds_read_b128
  __shared__ float4 s_w4v[1024];
  float* s_w4 = (float*)s_w4v;

  const int tid = threadIdx.x;
#pragma unroll
  for (int k = 0; k < 16; ++k) {
    int e = tid + 256 * k;          // e = j*512 + d
    int j = e >> 9, d = e & 511;
    s_w4[(j >> 2) * 2048 + d * 4 + (j & 3)] = w_in[e];
  }
  __syncthreads();

  const int lane   = tid & 63;
  const int wv     = tid >> 6;
  const int sample = blockIdx.x * 4 + wv;

  // ---------------- input GEMM: h_j = sum_d x[d] * w_in[j][d] ----------------
  const float* xrow = x + (size_t)sample * ND;
  float xv[8];
#pragma unroll
  for (int m = 0; m < 8; ++m) xv[m] = xrow[lane + 64 * m];

  float h[8];
#pragma unroll
  for (int j = 0; j < 8; ++j) h[j] = 0.f;
  const float4* w4 = (const float4*)s_w4v;
#pragma unroll
  for (int m = 0; m < 8; ++m) {
    const int d = lane + 64 * m;
    float4 w0 = w4[d];
    float4 w1 = w4[512 + d];
    h[0] += xv[m] * w0.x; h[1] += xv[m] * w0.y;
    h[2] += xv[m] * w0.z; h[3] += xv[m] * w0.w;
    h[4] += xv[m] * w1.x; h[5] += xv[m] * w1.y;
    h[6] += xv[m] * w1.z; h[7] += xv[m] * w1.w;
  }
#pragma unroll
  for (int j = 0; j < 8; ++j) h[j] = wave_sum(h[j]);

  // ---------------- tanh + LayerNorm + timestep -> angles ----------------
#pragma unroll
  for (int j = 0; j < 8; ++j) {
    float v = h[j] + b_in[j];
    v = fminf(15.f, fmaxf(-15.f, v));
    float e2 = __expf(2.f * v);
    h[j] = (e2 - 1.f) * __builtin_amdgcn_rcpf(e2 + 1.f);
  }
  float mu = 0.f;
#pragma unroll
  for (int j = 0; j < 8; ++j) mu += h[j];
  mu *= 0.125f;
  float var = 0.f;
#pragma unroll
  for (int j = 0; j < 8; ++j) { float d = h[j] - mu; var += d * d; }
  var *= 0.125f;
  const float rstd = rsqrtf(var + 1e-5f);
  const float t0 = tstep[0];
  float ang[8];
#pragma unroll
  for (int j = 0; j < 8; ++j) ang[j] = (h[j] - mu) * rstd * g[j] + be[j] + t0;

  // ---------------- per-qubit 1q state u_i = RZ(w1)RX(w0)RZ(a)RX(a)|0> ----------------
  float u0r[8], u0i[8], u1r[8], u1i[8];
#pragma unroll
  for (int i = 0; i < 8; ++i) {
    float sa, ca; __sincosf(ang[i] * 0.5f, &sa, &ca);
    float v0r = ca * ca, v0i = -ca * sa;
    float v1r = sa * sa, v1i = -sa * ca;
    float s0, c0; __sincosf(qw[0 * 9 + i] * 0.5f, &s0, &c0);
    float a0r = c0 * v0r + s0 * v1i;
    float a0i = c0 * v0i - s0 * v1r;
    float a1r = c0 * v1r + s0 * v0i;
    float a1i = c0 * v1i - s0 * v0r;
    float s1, c1; __sincosf(qw[1 * 9 + i] * 0.5f, &s1, &c1);
    u0r[i] = c1 * a0r + s1 * a0i;  u0i[i] = c1 * a0i - s1 * a0r;
    u1r[i] = c1 * a1r - s1 * a1i;  u1i[i] = c1 * a1i + s1 * a1r;
  }

  // ---------------- build product state ----------------
  float hr = 1.f, hi = 0.f;
  {
    const int wmap[5] = {4, 5, 3, 6, 7};    // lane bits 0..4 -> wires
#pragma unroll
    for (int b = 0; b < 5; ++b) {
      const int w = wmap[b];
      int bit = (lane >> b) & 1;
      float br  = bit ? u1r[w] : u0r[w];
      float bi_ = bit ? u1i[w] : u0i[w];
      float nr = hr * br - hi * bi_;
      float ni = hr * bi_ + hi * br;
      hr = nr; hi = ni;
    }
    if (lane & 32) { hr = 0.f; hi = 0.f; }  // ancilla |0>
  }
  float sr[8], si[8];
#pragma unroll
  for (int r = 0; r < 8; ++r) {
    float ar = (r & 1) ? u1r[0] : u0r[0];
    float ai = (r & 1) ? u1i[0] : u0i[0];
    float br = (r & 2) ? u1r[1] : u0r[1];
    float bi = (r & 2) ? u1i[1] : u0i[1];
    float t1r = ar * br - ai * bi, t1i = ar * bi + ai * br;
    float cr = (r & 4) ? u1r[2] : u0r[2];
    float ci = (r & 4) ? u1i[2] : u0i[2];
    float t2r = t1r * cr - t1i * ci, t2i = t1r * ci + t1i * cr;
    sr[r] = t2r * hr - t2i * hi;
    si[r] = t2r * hi + t2i * hr;
  }

  // ---------------- entangling layers l = 1..3 ----------------
#pragma unroll
  for (int l = 1; l < 4; ++l) {
    float gc[9], gs[9];
#pragma unroll
    for (int i = 0; i < 9; ++i) __sincosf(qw[l * 9 + i] * 0.5f, &gs[i], &gc[i]);

    cnot_ll<0, 1>(sr, si);                                  // CNOT(0,1)
    ry_local<0>(sr, si, gc[0], gs[0]); rz_local<0>(sr, si, gc[0], gs[0]);
    cnot_ll<1, 2>(sr, si);                                  // CNOT(1,2)
    ry_local<1>(sr, si, gc[1], gs[1]); rz_local<1>(sr, si, gc[1], gs[1]);
    cnot_lt<2, 4>(sr, si, lane);                            // CNOT(2,3)
    ry_local<2>(sr, si, gc[2], gs[2]); rz_local<2>(sr, si, gc[2], gs[2]);
    cnot_tt<4, 1>(sr, si, lane);                            // CNOT(3,4)
    { float se = (lane & 4) ? gs[3] : -gs[3];
      ry_lane<4>(sr, si, gc[3], se, lane); rz_lane(sr, si, gc[3], se); }
    cnot_tt<1, 2>(sr, si, lane);                            // CNOT(4,5)
    { float se = (lane & 1) ? gs[4] : -gs[4];
      ry_lane<1>(sr, si, gc[4], se, lane); rz_lane(sr, si, gc[4], se); }
    cnot_tt<2, 8>(sr, si, lane);                            // CNOT(5,6)
    { float se = (lane & 2) ? gs[5] : -gs[5];
      ry_lane<2>(sr, si, gc[5], se, lane); rz_lane(sr, si, gc[5], se); }
    cnot_tt<8, 16>(sr, si, lane);                           // CNOT(6,7)
    { float se = (lane & 8) ? gs[6] : -gs[6];
      ry_lane<8>(sr, si, gc[6], se, lane); rz_lane(sr, si, gc[6], se); }
    cnot_tl<0>(sr, si, 16, lane);                           // CNOT(7,0)
    { float se = (lane & 16) ? gs[7] : -gs[7];
      ry_lane<16>(sr, si, gc[7], se, lane); rz_lane(sr, si, gc[7], se); }
    cnot_tt<16, 32>(sr, si, lane);                          // CNOT(7,8)
    { float se = (lane & 32) ? gs[8] : -gs[8];
      ry_lane<32>(sr, si, gc[8], se, lane); }               // RY on ancilla
  }

  // ---------------- Z expectations ----------------
  float p[8];
#pragma unroll
  for (int r = 0; r < 8; ++r) p[r] = sr[r] * sr[r] + si[r] * si[r];
  float tot = 0.f;
#pragma unroll
  for (int r = 0; r < 8; ++r) tot += p[r];

  float z[8];
  z[0] = (p[0] - p[1]) + (p[2] - p[3]) + (p[4] - p[5]) + (p[6] - p[7]);
  z[1] = (p[0] + p[1]) - (p[2] + p[3]) + (p[4] + p[5]) - (p[6] + p[7]);
  z[2] = (p[0] + p[1] + p[2] + p[3]) - (p[4] + p[5] + p[6] + p[7]);
  // wires 3..7 -> lane masks {4,1,2,8,16}
  z[3] = (lane & 4)  ? -tot : tot;
  z[4] = (lane & 1)  ? -tot : tot;
  z[5] = (lane & 2)  ? -tot : tot;
  z[6] = (lane & 8)  ? -tot : tot;
  z[7] = (lane & 16) ? -tot : tot;
#pragma unroll
  for (int j = 0; j < 8; ++j) z[j] = wave_sum(z[j]);

  // ---------------- epilogue: out = x + z @ w_out^T + b_out ----------------
  const size_t base = (size_t)sample * ND;
  const float4* wo4 = (const float4*)w_out;   // [512][8]: 2x float4 per d
#pragma unroll
  for (int m = 0; m < 8; ++m) {
    const int d = lane + 64 * m;
    float4 a  = wo4[2 * d];
    float4 b4 = wo4[2 * d + 1];
    float o = xv[m] + b_out[d];
    o += z[0] * a.x  + z[1] * a.y  + z[2] * a.z  + z[3] * a.w;
    o += z[4] * b4.x + z[5] * b4.y + z[6] * b4.z + z[7] * b4.w;
    out[base + d] = o;
  }
}

extern "C" void kernel_launch(void* const* d_in, const int* in_sizes, int n_in,
                              void* d_out, int out_size, void* d_ws, size_t ws_size,
                              hipStream_t stream) {
  const float* x     = (const float*)d_in[0];
  const float* ts    = (const float*)d_in[1];
  const float* w_in  = (const float*)d_in[2];
  const float* b_in  = (const float*)d_in[3];
  const float* g     = (const float*)d_in[4];
  const float* be    = (const float*)d_in[5];
  const float* qw    = (const float*)d_in[6];
  const float* w_out = (const float*)d_in[7];
  const float* b_out = (const float*)d_in[8];
  float* out = (float*)d_out;

  qlayer_kernel<<<dim3(NSAMP / 4), dim3(256), 0, stream>>>(
      x, ts, w_in, b_in, g, be, qw, w_out, b_out, out);
}

// Round 4
// 82.170 us; speedup vs baseline: 1.6121x; 1.4563x over previous
//
#include <hip/hip_runtime.h>
#include <math.h>

#define NSAMP 16384
#define ND    512

typedef float f2 __attribute__((ext_vector_type(2)));

__device__ __forceinline__ f2 spl(float x) { return (f2){x, x}; }

// ---------------- cross-lane primitives ----------------
template<int CTRL>
__device__ __forceinline__ float dppf(float x) {
  return __int_as_float(__builtin_amdgcn_update_dpp(
      __float_as_int(x), __float_as_int(x), CTRL, 0xF, 0xF, true));
}
// masked DPP: only rows in RM / banks in BM write; others keep self (old)
template<int CTRL, int RM, int BM>
__device__ __forceinline__ float dppf_keep(float x) {
  return __int_as_float(__builtin_amdgcn_update_dpp(
      __float_as_int(x), __float_as_int(x), CTRL, RM, BM, false));
}
template<int P>
__device__ __forceinline__ float swzf(float x) {
  return __int_as_float(__builtin_amdgcn_ds_swizzle(__float_as_int(x), P));
}

#if __has_builtin(__builtin_amdgcn_permlane16_swap)
#define HAVE_PLSWAP 1
#endif
__device__ __forceinline__ void plswap16(float x, float& a, float& b) {
#ifdef HAVE_PLSWAP
  auto r = __builtin_amdgcn_permlane16_swap(__float_as_uint(x), __float_as_uint(x), false, false);
  a = __uint_as_float(r[0]); b = __uint_as_float(r[1]);
#else
  a = x; b = swzf<0x401F>(x);
#endif
}
__device__ __forceinline__ void plswap32(float x, float& a, float& b) {
#ifdef HAVE_PLSWAP
  auto r = __builtin_amdgcn_permlane32_swap(__float_as_uint(x), __float_as_uint(x), false, false);
  a = __uint_as_float(r[0]); b = __uint_as_float(r[1]);
#else
  a = x; b = __shfl_xor(x, 32, 64);
#endif
}

// full 64-lane sum all-reduce, pure VALU
__device__ __forceinline__ float wave_sum(float x) {
  x += dppf<0xB1>(x);                           // xor1
  x += dppf<0x4E>(x);                           // xor2
  x += dppf<0x124>(x);                          // row_ror:4
  x += dppf<0x128>(x);                          // row_ror:8
  { float a, b; plswap16(x, a, b); x = a + b; }
  { float a, b; plswap32(x, a, b); x = a + b; }
  return x;
}

// butterfly exchange of an (re,im) pair: value of lane (lane ^ M)
template<int M>
__device__ __forceinline__ f2 bfly2(f2 x) {
  f2 r;
  if constexpr (M == 1)       { r.x = dppf<0xB1>(x.x);    r.y = dppf<0xB1>(x.y); }
  else if constexpr (M == 2)  { r.x = dppf<0x4E>(x.x);    r.y = dppf<0x4E>(x.y); }
  else if constexpr (M == 8)  { r.x = dppf<0x128>(x.x);   r.y = dppf<0x128>(x.y); }
  else if constexpr (M == 4)  { r.x = swzf<0x101F>(x.x);  r.y = swzf<0x101F>(x.y); }
  else if constexpr (M == 16) { r.x = swzf<0x401F>(x.x);  r.y = swzf<0x401F>(x.y); }
  else                        { r.x = __shfl_xor(x.x, 32, 64); r.y = __shfl_xor(x.y, 32, 64); }
  return r;
}

// complex multiply (2 packed ops: pk_mul + pk_fma with op_sel/neg folding)
__device__ __forceinline__ f2 cmul(f2 a, f2 b) {
  f2 bs = __builtin_shufflevector(b, b, 1, 0);   // (bi, br)
  f2 t  = (f2){-a.y, a.y} * bs;                  // (-ai*bi, ai*br)
  return spl(a.x) * b + t;                       // (ar*br - ai*bi, ar*bi + ai*br)
}

// ---------------- gates (state = 8 packed complex amps per lane) ----------------
template<int LB>
__device__ __forceinline__ void ry_local(f2* s, float c, float sv) {
#pragma unroll
  for (int r0 = 0; r0 < 8; ++r0) {
    if (r0 & (1 << LB)) continue;
    const int r1 = r0 | (1 << LB);
    f2 a0 = s[r0], a1 = s[r1];
    s[r0] = spl(c) * a0 - spl(sv) * a1;
    s[r1] = spl(sv) * a0 + spl(c) * a1;
  }
}
template<int LB>
__device__ __forceinline__ void rz_local(f2* s, f2 phm, f2 php) {
#pragma unroll
  for (int r = 0; r < 8; ++r) s[r] = cmul(s[r], (r & (1 << LB)) ? php : phm);
}
// diagonal on a lane wire: multiply all amps by per-lane phase (c, se)
__device__ __forceinline__ void rz_lane(f2* s, f2 ph) {
#pragma unroll
  for (int r = 0; r < 8; ++r) s[r] = cmul(s[r], ph);
}
template<int M>
__device__ __forceinline__ void ry_lane(f2* s, float c, float se) {
#pragma unroll
  for (int r = 0; r < 8; ++r) {
    f2 p = bfly2<M>(s[r]);
    s[r] = spl(c) * s[r] + spl(se) * p;
  }
}
template<int CB, int TB>
__device__ __forceinline__ void cnot_ll(f2* s) {
#pragma unroll
  for (int r0 = 0; r0 < 8; ++r0) {
    if (!(r0 & (1 << CB)) || (r0 & (1 << TB))) continue;
    const int r1 = r0 | (1 << TB);
    f2 t = s[r0]; s[r0] = s[r1]; s[r1] = t;
  }
}
template<int CB, int TM>
__device__ __forceinline__ void cnot_lt(f2* s) {
#pragma unroll
  for (int r = 0; r < 8; ++r) {
    if (!(r & (1 << CB))) continue;
    s[r] = bfly2<TM>(s[r]);
  }
}
template<int CM, int TM>
__device__ __forceinline__ void cnot_tt(f2* s, bool cc) {
#pragma unroll
  for (int r = 0; r < 8; ++r) {
    f2 p = bfly2<TM>(s[r]);
    s[r].x = cc ? p.x : s[r].x;
    s[r].y = cc ? p.y : s[r].y;
  }
}
// CNOT ctrl=mask4, tgt=mask1: ctrl lanes are DPP banks 1,3 -> masked quad_perm,
// disabled banks keep self (old). One instruction per 32-bit half.
__device__ __forceinline__ void cnot_m4_t1(f2* s) {
#pragma unroll
  for (int r = 0; r < 8; ++r) {
    s[r].x = dppf_keep<0xB1, 0xF, 0xA>(s[r].x);
    s[r].y = dppf_keep<0xB1, 0xF, 0xA>(s[r].y);
  }
}
template<int TB>
__device__ __forceinline__ void cnot_tl(f2* s, bool cc) {
#pragma unroll
  for (int r0 = 0; r0 < 8; ++r0) {
    if (r0 & (1 << TB)) continue;
    const int r1 = r0 | (1 << TB);
    f2 n0, n1;
    n0.x = cc ? s[r1].x : s[r0].x;  n0.y = cc ? s[r1].y : s[r0].y;
    n1.x = cc ? s[r0].x : s[r1].x;  n1.y = cc ? s[r0].y : s[r1].y;
    s[r0] = n0; s[r1] = n1;
  }
}

// ---------------- precomputed weight constants ----------------
// ws[0..53]:  (c,s) of qw[l*9+i]/2 for l=1..3, i=0..8  (f2 index (l-1)*9+i)
// ws[64..127]: per qubit i: M = RZ(w1)RX(w0) as 4 complex (M00,M01,M10,M11)
__global__ void qpre_kernel(const float* __restrict__ qw, float* __restrict__ ws) {
  int t = threadIdx.x;
  if (t < 27) {
    float s, c; __sincosf(qw[9 + t] * 0.5f, &s, &c);
    ws[2 * t] = c; ws[2 * t + 1] = s;
  }
  if (t < 8) {
    float s0, c0, s1, c1;
    __sincosf(qw[t] * 0.5f, &s0, &c0);
    __sincosf(qw[9 + t] * 0.5f, &s1, &c1);
    float* m = ws + 64 + t * 8;
    m[0] =  c1 * c0;  m[1] = -s1 * c0;   // M00
    m[2] = -s1 * s0;  m[3] = -c1 * s0;   // M01
    m[4] =  s1 * s0;  m[5] = -c1 * s0;   // M10
    m[6] =  c1 * c0;  m[7] =  s1 * c0;   // M11
  }
}

template<bool PRE>
struct Consts {
  const float* qw; const float* ws;
  __device__ __forceinline__ f2 ltrig(int l, int i) const {
    if constexpr (PRE) {
      return ((const f2*)ws)[(l - 1) * 9 + i];
    } else {
      float s, c; __sincosf(qw[l * 9 + i] * 0.5f, &s, &c);
      return (f2){c, s};
    }
  }
  __device__ __forceinline__ void getM(int i, f2& M00, f2& M01, f2& M10, f2& M11) const {
    if constexpr (PRE) {
      const f2* m = (const f2*)(ws + 64 + i * 8);
      M00 = m[0]; M01 = m[1]; M10 = m[2]; M11 = m[3];
    } else {
      float s0, c0, s1, c1;
      __sincosf(qw[i] * 0.5f, &s0, &c0);
      __sincosf(qw[9 + i] * 0.5f, &s1, &c1);
      M00 = (f2){ c1 * c0, -s1 * c0};
      M01 = (f2){-s1 * s0, -c1 * s0};
      M10 = (f2){ s1 * s0, -c1 * s0};
      M11 = (f2){ c1 * c0,  s1 * c0};
    }
  }
};

// Wire->lane-bit map (wires 0,1,2 = register bits 0,1,2):
//   wire4->m1, wire5->m2, wire3->m4, wire6->m8, wire7->m16, wire8(anc)->m32
template<bool PRE>
__global__ __launch_bounds__(256, 4) void qlayer_kernel(
    const float* __restrict__ x, const float* __restrict__ tstep,
    const float* __restrict__ w_in, const float* __restrict__ b_in,
    const float* __restrict__ g, const float* __restrict__ be,
    const float* __restrict__ qw, const float* __restrict__ w_out,
    const float* __restrict__ b_out, float* __restrict__ out,
    const float* __restrict__ ws)
{
  __shared__ float4 s_w4v[1024];   // w_in transposed-packed: [j_hi][d][j_lo4]
  float* s_w4 = (float*)s_w4v;

  const int tid = threadIdx.x;
#pragma unroll
  for (int k = 0; k < 16; ++k) {
    int e = tid + 256 * k;          // e = j*512 + d
    int j = e >> 9, d = e & 511;
    s_w4[(j >> 2) * 2048 + d * 4 + (j & 3)] = w_in[e];
  }
  __syncthreads();

  const int lane   = tid & 63;
  const int wv     = tid >> 6;
  const int sample = blockIdx.x * 4 + wv;

  // ---------------- input GEMM (packed) ----------------
  const float* xrow = x + (size_t)sample * ND;
  float xv[8];
#pragma unroll
  for (int m = 0; m < 8; ++m) xv[m] = xrow[lane + 64 * m];

  f2 hA = (f2){0.f, 0.f}, hB = hA, hC = hA, hD = hA;
  const float4* w4 = (const float4*)s_w4v;
#pragma unroll
  for (int m = 0; m < 8; ++m) {
    const int d = lane + 64 * m;
    float4 w0 = w4[d];
    float4 w1 = w4[512 + d];
    f2 xm = spl(xv[m]);
    hA += xm * (f2){w0.x, w0.y};  hB += xm * (f2){w0.z, w0.w};
    hC += xm * (f2){w1.x, w1.y};  hD += xm * (f2){w1.z, w1.w};
  }
  float h[8] = {hA.x, hA.y, hB.x, hB.y, hC.x, hC.y, hD.x, hD.y};
#pragma unroll
  for (int j = 0; j < 8; ++j) h[j] = wave_sum(h[j]);

  // ---------------- tanh + LayerNorm + timestep -> angles ----------------
#pragma unroll
  for (int j = 0; j < 8; ++j) {
    float v = h[j] + b_in[j];
    v = fminf(15.f, fmaxf(-15.f, v));
    float e2 = __expf(2.f * v);
    h[j] = (e2 - 1.f) * __builtin_amdgcn_rcpf(e2 + 1.f);
  }
  float mu = 0.f;
#pragma unroll
  for (int j = 0; j < 8; ++j) mu += h[j];
  mu *= 0.125f;
  float var = 0.f;
#pragma unroll
  for (int j = 0; j < 8; ++j) { float d = h[j] - mu; var += d * d; }
  var *= 0.125f;
  const float rstd = rsqrtf(var + 1e-5f);
  const float t0 = tstep[0];
  float ang[8];
#pragma unroll
  for (int j = 0; j < 8; ++j) ang[j] = (h[j] - mu) * rstd * g[j] + be[j] + t0;

  Consts<PRE> cst{qw, ws};

  // ---------------- per-qubit u_i = M_i * (RZ(a)RX(a)|0>) ----------------
  f2 u0[8], u1[8];
#pragma unroll
  for (int i = 0; i < 8; ++i) {
    float sa, ca; __sincosf(ang[i] * 0.5f, &sa, &ca);
    f2 v0 = spl(ca) * (f2){ca, -sa};
    f2 v1 = spl(sa) * (f2){sa, -ca};
    f2 M00, M01, M10, M11; cst.getM(i, M00, M01, M10, M11);
    u0[i] = cmul(M00, v0) + cmul(M01, v1);
    u1[i] = cmul(M10, v0) + cmul(M11, v1);
  }

  // ---------------- build product state ----------------
  f2 hl;
  {
    hl = (lane & 1) ? u1[4] : u0[4];                 // lane bit0 -> wire4
    f2 b;
    b = (lane & 2)  ? u1[5] : u0[5]; hl = cmul(hl, b);   // bit1 -> wire5
    b = (lane & 4)  ? u1[3] : u0[3]; hl = cmul(hl, b);   // bit2 -> wire3
    b = (lane & 8)  ? u1[6] : u0[6]; hl = cmul(hl, b);   // bit3 -> wire6
    b = (lane & 16) ? u1[7] : u0[7]; hl = cmul(hl, b);   // bit4 -> wire7
    if (lane & 32) hl = (f2){0.f, 0.f};                  // ancilla |0>
  }
  f2 t01[4];
#pragma unroll
  for (int q = 0; q < 4; ++q)
    t01[q] = cmul((q & 1) ? u1[0] : u0[0], (q & 2) ? u1[1] : u0[1]);
  f2 st[8];
#pragma unroll
  for (int r = 0; r < 8; ++r)
    st[r] = cmul(cmul(t01[r & 3], (r & 4) ? u1[2] : u0[2]), hl);

  // ---------------- entangling layers l = 1..3 ----------------
#pragma unroll
  for (int l = 1; l < 4; ++l) {
    f2 t[9];
#pragma unroll
    for (int i = 0; i < 9; ++i) t[i] = cst.ltrig(l, i);

    cnot_ll<0, 1>(st);                                       // CNOT(0,1)
    ry_local<0>(st, t[0].x, t[0].y);
    rz_local<0>(st, (f2){t[0].x, -t[0].y}, (f2){t[0].x, t[0].y});
    cnot_ll<1, 2>(st);                                       // CNOT(1,2)
    ry_local<1>(st, t[1].x, t[1].y);
    rz_local<1>(st, (f2){t[1].x, -t[1].y}, (f2){t[1].x, t[1].y});
    cnot_lt<2, 4>(st);                                       // CNOT(2,3)
    ry_local<2>(st, t[2].x, t[2].y);
    rz_local<2>(st, (f2){t[2].x, -t[2].y}, (f2){t[2].x, t[2].y});
    cnot_m4_t1(st);                                          // CNOT(3,4)
    { float se = (lane & 4) ? t[3].y : -t[3].y;
      ry_lane<4>(st, t[3].x, se); rz_lane(st, (f2){t[3].x, se}); }
    cnot_tt<1, 2>(st, (lane & 1) != 0);                      // CNOT(4,5)
    { float se = (lane & 1) ? t[4].y : -t[4].y;
      ry_lane<1>(st, t[4].x, se); rz_lane(st, (f2){t[4].x, se}); }
    cnot_tt<2, 8>(st, (lane & 2) != 0);                      // CNOT(5,6)
    { float se = (lane & 2) ? t[5].y : -t[5].y;
      ry_lane<2>(st, t[5].x, se); rz_lane(st, (f2){t[5].x, se}); }
    cnot_tt<8, 16>(st, (lane & 8) != 0);                     // CNOT(6,7)
    { float se = (lane & 8) ? t[6].y : -t[6].y;
      ry_lane<8>(st, t[6].x, se); rz_lane(st, (f2){t[6].x, se}); }
    cnot_tl<0>(st, (lane & 16) != 0);                        // CNOT(7,0)
    { float se = (lane & 16) ? t[7].y : -t[7].y;
      ry_lane<16>(st, t[7].x, se); rz_lane(st, (f2){t[7].x, se}); }
    cnot_tt<16, 32>(st, (lane & 16) != 0);                   // CNOT(7,8)
    { float se = (lane & 32) ? t[8].y : -t[8].y;
      ry_lane<32>(st, t[8].x, se); }                         // RY on ancilla
  }

  // ---------------- Z expectations ----------------
  float p[8];
#pragma unroll
  for (int r = 0; r < 8; ++r) p[r] = st[r].x * st[r].x + st[r].y * st[r].y;
  float tot = 0.f;
#pragma unroll
  for (int r = 0; r < 8; ++r) tot += p[r];

  float z[8];
  z[0] = (p[0] - p[1]) + (p[2] - p[3]) + (p[4] - p[5]) + (p[6] - p[7]);
  z[1] = (p[0] + p[1]) - (p[2] + p[3]) + (p[4] + p[5]) - (p[6] + p[7]);
  z[2] = (p[0] + p[1] + p[2] + p[3]) - (p[4] + p[5] + p[6] + p[7]);
  z[3] = (lane & 4)  ? -tot : tot;
  z[4] = (lane & 1)  ? -tot : tot;
  z[5] = (lane & 2)  ? -tot : tot;
  z[6] = (lane & 8)  ? -tot : tot;
  z[7] = (lane & 16) ? -tot : tot;
#pragma unroll
  for (int j = 0; j < 8; ++j) z[j] = wave_sum(z[j]);

  // ---------------- epilogue: out = x + z @ w_out^T + b_out ----------------
  const size_t base = (size_t)sample * ND;
  const float4* wo4 = (const float4*)w_out;   // [512][8]
  f2 z01 = (f2){z[0], z[1]}, z23 = (f2){z[2], z[3]};
  f2 z45 = (f2){z[4], z[5]}, z67 = (f2){z[6], z[7]};
#pragma unroll
  for (int m = 0; m < 8; ++m) {
    const int d = lane + 64 * m;
    float4 a  = wo4[2 * d];
    float4 b4 = wo4[2 * d + 1];
    f2 acc = z01 * (f2){a.x, a.y};
    acc += z23 * (f2){a.z, a.w};
    acc += z45 * (f2){b4.x, b4.y};
    acc += z67 * (f2){b4.z, b4.w};
    out[base + d] = xv[m] + b_out[d] + acc.x + acc.y;
  }
}

extern "C" void kernel_launch(void* const* d_in, const int* in_sizes, int n_in,
                              void* d_out, int out_size, void* d_ws, size_t ws_size,
                              hipStream_t stream) {
  const float* x     = (const float*)d_in[0];
  const float* ts    = (const float*)d_in[1];
  const float* w_in  = (const float*)d_in[2];
  const float* b_in  = (const float*)d_in[3];
  const float* g     = (const float*)d_in[4];
  const float* be    = (const float*)d_in[5];
  const float* qw    = (const float*)d_in[6];
  const float* w_out = (const float*)d_in[7];
  const float* b_out = (const float*)d_in[8];
  float* out = (float*)d_out;

  const bool pre = (d_ws != nullptr) && (ws_size >= 1024);
  if (pre) {
    qpre_kernel<<<dim3(1), dim3(64), 0, stream>>>(qw, (float*)d_ws);
    qlayer_kernel<true><<<dim3(NSAMP / 4), dim3(256), 0, stream>>>(
        x, ts, w_in, b_in, g, be, qw, w_out, b_out, out, (const float*)d_ws);
  } else {
    qlayer_kernel<false><<<dim3(NSAMP / 4), dim3(256), 0, stream>>>(
        x, ts, w_in, b_in, g, be, qw, w_out, b_out, out, (const float*)d_ws);
  }
}

// Round 5
// 58.464 us; speedup vs baseline: 2.2657x; 1.4055x over previous
//
#include <hip/hip_runtime.h>
#include <math.h>

#define NSAMP 16384
#define ND    512

typedef float f2 __attribute__((ext_vector_type(2)));
__device__ __forceinline__ f2 spl(float x) { return (f2){x, x}; }

// ---------------- cross-lane primitives ----------------
template<int CTRL>
__device__ __forceinline__ float dppf(float x) {
  return __int_as_float(__builtin_amdgcn_update_dpp(
      __float_as_int(x), __float_as_int(x), CTRL, 0xF, 0xF, true));
}
template<int CTRL, int RM, int BM>
__device__ __forceinline__ float dppf_keep(float x) {
  return __int_as_float(__builtin_amdgcn_update_dpp(
      __float_as_int(x), __float_as_int(x), CTRL, RM, BM, false));
}
template<int P>
__device__ __forceinline__ float swzf(float x) {
  return __int_as_float(__builtin_amdgcn_ds_swizzle(__float_as_int(x), P));
}

#if __has_builtin(__builtin_amdgcn_permlane16_swap)
#define HAVE_PLSWAP 1
#endif
__device__ __forceinline__ void plswap16(float x, float& a, float& b) {
#ifdef HAVE_PLSWAP
  auto r = __builtin_amdgcn_permlane16_swap(__float_as_uint(x), __float_as_uint(x), false, false);
  a = __uint_as_float(r[0]); b = __uint_as_float(r[1]);
#else
  a = x; b = swzf<0x401F>(x);
#endif
}
__device__ __forceinline__ void plswap32(float x, float& a, float& b) {
#ifdef HAVE_PLSWAP
  auto r = __builtin_amdgcn_permlane32_swap(__float_as_uint(x), __float_as_uint(x), false, false);
  a = __uint_as_float(r[0]); b = __uint_as_float(r[1]);
#else
  a = x; b = __shfl_xor(x, 32, 64);
#endif
}

// butterfly exchange of an (re,im) pair: value of lane (lane ^ M)
template<int M>
__device__ __forceinline__ f2 bfly2(f2 x) {
  f2 r;
  if constexpr (M == 1)       { r.x = dppf<0xB1>(x.x);    r.y = dppf<0xB1>(x.y); }
  else if constexpr (M == 2)  { r.x = dppf<0x4E>(x.x);    r.y = dppf<0x4E>(x.y); }
  else if constexpr (M == 8)  { r.x = dppf<0x128>(x.x);   r.y = dppf<0x128>(x.y); }
  else if constexpr (M == 4)  { r.x = swzf<0x101F>(x.x);  r.y = swzf<0x101F>(x.y); }
  else if constexpr (M == 16) { r.x = swzf<0x401F>(x.x);  r.y = swzf<0x401F>(x.y); }
  else                        { r.x = __shfl_xor(x.x, 32, 64); r.y = __shfl_xor(x.y, 32, 64); }
  return r;
}

// sum over all 64 lanes of y[lane&7]; result on every lane (for its own j)
__device__ __forceinline__ float fold8_allsum(const float* y, int lane) {
  float v4[4];
#pragma unroll
  for (int i = 0; i < 4; ++i) {
    float keep = (lane & 1) ? y[2 * i + 1] : y[2 * i];
    float send = (lane & 1) ? y[2 * i]     : y[2 * i + 1];
    v4[i] = keep + dppf<0xB1>(send);
  }
  float v2[2];
#pragma unroll
  for (int i = 0; i < 2; ++i) {
    float keep = (lane & 2) ? v4[2 * i + 1] : v4[2 * i];
    float send = (lane & 2) ? v4[2 * i]     : v4[2 * i + 1];
    v2[i] = keep + dppf<0x4E>(send);
  }
  float keep = (lane & 4) ? v2[1] : v2[0];
  float send = (lane & 4) ? v2[0] : v2[1];
  float r = keep + swzf<0x101F>(send);
  r += dppf<0x128>(r);                          // xor8
  { float a, b; plswap16(r, a, b); r = a + b; } // +xor16
  { float a, b; plswap32(r, a, b); r = a + b; } // +xor32
  return r;
}

// all-reduce sum within each 8-lane group
__device__ __forceinline__ float grp8_sum(float x) {
  x += dppf<0xB1>(x);
  x += dppf<0x4E>(x);
  x += swzf<0x101F>(x);
  return x;
}

// complex multiply
__device__ __forceinline__ f2 cmul(f2 a, f2 b) {
  f2 bs = __builtin_shufflevector(b, b, 1, 0);
  f2 t  = (f2){-a.y, a.y} * bs;
  return spl(a.x) * b + t;
}

// ---------------- gates ----------------
template<int LB>
__device__ __forceinline__ void ry_local(f2* s, float c, float sv) {
#pragma unroll
  for (int r0 = 0; r0 < 8; ++r0) {
    if (r0 & (1 << LB)) continue;
    const int r1 = r0 | (1 << LB);
    f2 a0 = s[r0], a1 = s[r1];
    s[r0] = spl(c) * a0 - spl(sv) * a1;
    s[r1] = spl(sv) * a0 + spl(c) * a1;
  }
}
template<int LB>
__device__ __forceinline__ void rz_local(f2* s, f2 phm, f2 php) {
#pragma unroll
  for (int r = 0; r < 8; ++r) s[r] = cmul(s[r], (r & (1 << LB)) ? php : phm);
}
template<int M>
__device__ __forceinline__ void ry_lane(f2* s, float c, float se) {
#pragma unroll
  for (int r = 0; r < 8; ++r) {
    f2 p = bfly2<M>(s[r]);
    s[r] = spl(c) * s[r] + spl(se) * p;
  }
}
template<int CB, int TB>
__device__ __forceinline__ void cnot_ll(f2* s) {
#pragma unroll
  for (int r0 = 0; r0 < 8; ++r0) {
    if (!(r0 & (1 << CB)) || (r0 & (1 << TB))) continue;
    const int r1 = r0 | (1 << TB);
    f2 t = s[r0]; s[r0] = s[r1]; s[r1] = t;
  }
}
template<int CB, int TM>
__device__ __forceinline__ void cnot_lt(f2* s) {
#pragma unroll
  for (int r = 0; r < 8; ++r) {
    if (!(r & (1 << CB))) continue;
    s[r] = bfly2<TM>(s[r]);
  }
}
template<int CM, int TM>
__device__ __forceinline__ void cnot_tt(f2* s, bool cc) {
#pragma unroll
  for (int r = 0; r < 8; ++r) {
    f2 p = bfly2<TM>(s[r]);
    s[r].x = cc ? p.x : s[r].x;
    s[r].y = cc ? p.y : s[r].y;
  }
}
// CNOT ctrl=m4 (banks 1,3), tgt=m1: masked quad_perm, others keep old
__device__ __forceinline__ void cnot_m4_t1(f2* s) {
#pragma unroll
  for (int r = 0; r < 8; ++r) {
    s[r].x = dppf_keep<0xB1, 0xF, 0xA>(s[r].x);
    s[r].y = dppf_keep<0xB1, 0xF, 0xA>(s[r].y);
  }
}
// CNOT ctrl=m1, tgt=m2: full quad_perm [0,3,2,1]
__device__ __forceinline__ void cnot_m1_t2(f2* s) {
#pragma unroll
  for (int r = 0; r < 8; ++r) {
    s[r].x = dppf<0x6C>(s[r].x);
    s[r].y = dppf<0x6C>(s[r].y);
  }
}
template<int TB>
__device__ __forceinline__ void cnot_tl(f2* s, bool cc) {
#pragma unroll
  for (int r0 = 0; r0 < 8; ++r0) {
    if (r0 & (1 << TB)) continue;
    const int r1 = r0 | (1 << TB);
    f2 n0, n1;
    n0.x = cc ? s[r1].x : s[r0].x;  n0.y = cc ? s[r1].y : s[r0].y;
    n1.x = cc ? s[r0].x : s[r1].x;  n1.y = cc ? s[r0].y : s[r1].y;
    s[r0] = n0; s[r1] = n1;
  }
}

// ---------------- prekernel: layer trig table ----------------
// ws[0..53]: (c,s) of qw[l*9+i]/2 for l=1..3, i=0..8  (f2 index (l-1)*9+i)
__global__ void qpre_kernel(const float* __restrict__ qw, float* __restrict__ ws) {
  int t = threadIdx.x;
  if (t < 27) {
    float s, c; __sincosf(qw[9 + t] * 0.5f, &s, &c);
    ws[2 * t] = c; ws[2 * t + 1] = s;
  }
}

template<bool PRE>
struct Consts {
  const float* qw; const float* ws;
  __device__ __forceinline__ f2 ltrig(int l, int i) const {
    if constexpr (PRE) {
      return ((const f2*)ws)[(l - 1) * 9 + i];
    } else {
      float s, c; __sincosf(qw[l * 9 + i] * 0.5f, &s, &c);
      return (f2){c, s};
    }
  }
};

// One entangling layer. FULL=false (last layer): skip CNOT(7,8), RY(8) and the
// merged deferred phase — all provably leave measured marginals invariant.
// Deferred RZs (wires 1,2 local; 3..7 lane) commute to layer end: each wire is
// only ever a CNOT *control* (diagonal-commuting) after its RZ point.
template<bool PRE, bool FULL>
__device__ __forceinline__ void do_layer(f2* st, int lane, const Consts<PRE>& cst, int l) {
  f2 t[9];
#pragma unroll
  for (int i = 0; i < 9; ++i) t[i] = cst.ltrig(l, i);

  cnot_ll<0, 1>(st);                                       // CNOT(0,1)
  ry_local<0>(st, t[0].x, t[0].y);
  rz_local<0>(st, (f2){t[0].x, -t[0].y}, (f2){t[0].x, t[0].y});  // Z0 inline
  cnot_ll<1, 2>(st);                                       // CNOT(1,2)
  ry_local<1>(st, t[1].x, t[1].y);                         // Z1 deferred
  cnot_lt<2, 4>(st);                                       // CNOT(2,3)
  ry_local<2>(st, t[2].x, t[2].y);                         // Z2 deferred
  cnot_m4_t1(st);                                          // CNOT(3,4)
  { float se = (lane & 4) ? t[3].y : -t[3].y;
    ry_lane<4>(st, t[3].x, se); }                          // Z3 deferred
  cnot_m1_t2(st);                                          // CNOT(4,5)
  { float se = (lane & 1) ? t[4].y : -t[4].y;
    ry_lane<1>(st, t[4].x, se); }                          // Z4 deferred
  cnot_tt<2, 8>(st, (lane & 2) != 0);                      // CNOT(5,6)
  { float se = (lane & 2) ? t[5].y : -t[5].y;
    ry_lane<2>(st, t[5].x, se); }                          // Z5 deferred
  cnot_tt<8, 16>(st, (lane & 8) != 0);                     // CNOT(6,7)
  { float se = (lane & 8) ? t[6].y : -t[6].y;
    ry_lane<8>(st, t[6].x, se); }                          // Z6 deferred
  cnot_tl<0>(st, (lane & 16) != 0);                        // CNOT(7,0)
  { float se = (lane & 16) ? t[7].y : -t[7].y;
    ry_lane<16>(st, t[7].x, se); }                         // Z7 deferred

  if constexpr (FULL) {
    cnot_tt<16, 32>(st, (lane & 16) != 0);                 // CNOT(7,8)
    { float se = (lane & 32) ? t[8].y : -t[8].y;
      ry_lane<32>(st, t[8].x, se); }                       // RY(8)
    // merged deferred phase: local part (wires 1,2 on reg bits 1,2)
    f2 L4[4];
#pragma unroll
    for (int k = 0; k < 4; ++k) {
      f2 p1 = (f2){t[1].x, (k & 1) ? t[1].y : -t[1].y};
      f2 p2 = (f2){t[2].x, (k & 2) ? t[2].y : -t[2].y};
      L4[k] = cmul(p1, p2);
    }
    // lane part: wires 3..7 on masks {4,1,2,8,16}
    f2 phW = (f2){t[3].x, (lane & 4)  ? t[3].y : -t[3].y};
    phW = cmul(phW, (f2){t[4].x, (lane & 1)  ? t[4].y : -t[4].y});
    phW = cmul(phW, (f2){t[5].x, (lane & 2)  ? t[5].y : -t[5].y});
    phW = cmul(phW, (f2){t[6].x, (lane & 8)  ? t[6].y : -t[6].y});
    phW = cmul(phW, (f2){t[7].x, (lane & 16) ? t[7].y : -t[7].y});
    f2 pr[4];
#pragma unroll
    for (int k = 0; k < 4; ++k) pr[k] = cmul(L4[k], phW);
#pragma unroll
    for (int r = 0; r < 8; ++r) st[r] = cmul(st[r], pr[(r >> 1) & 3]);
  }
}

// Wire->lane-bit map (wires 0,1,2 = register bits 0,1,2):
//   wire4->m1, wire5->m2, wire3->m4, wire6->m8, wire7->m16, wire8(anc)->m32
template<bool PRE>
__global__ __launch_bounds__(256, 4) void qlayer_kernel(
    const float* __restrict__ x, const float* __restrict__ tstep,
    const float* __restrict__ w_in, const float* __restrict__ b_in,
    const float* __restrict__ g, const float* __restrict__ be,
    const float* __restrict__ qw, const float* __restrict__ w_out,
    const float* __restrict__ b_out, float* __restrict__ out,
    const float* __restrict__ ws)
{
  __shared__ float4 s_w4v[1024];            // w_in transposed-packed [j_hi][d][j_lo4]
  __shared__ __align__(16) float s_u[4][8][4];  // per-wave u table
  __shared__ __align__(16) float s_z[4][8];     // per-wave z table
  float* s_w4 = (float*)s_w4v;

  const int tid = threadIdx.x;
#pragma unroll
  for (int k = 0; k < 16; ++k) {
    int e = tid + 256 * k;          // e = j*512 + d
    int j = e >> 9, d = e & 511;
    s_w4[(j >> 2) * 2048 + d * 4 + (j & 3)] = w_in[e];
  }
  __syncthreads();

  const int lane   = tid & 63;
  const int wv     = tid >> 6;
  const int sample = blockIdx.x * 4 + wv;
  const int jq     = lane & 7;              // this lane's owned qubit

  // ---------------- input GEMM (packed partials) ----------------
  const float* xrow = x + (size_t)sample * ND;
  float xv[8];
#pragma unroll
  for (int m = 0; m < 8; ++m) xv[m] = xrow[lane + 64 * m];

  f2 hA = (f2){0.f, 0.f}, hB = hA, hC = hA, hD = hA;
  const float4* w4 = (const float4*)s_w4v;
#pragma unroll
  for (int m = 0; m < 8; ++m) {
    const int d = lane + 64 * m;
    float4 w0 = w4[d];
    float4 w1 = w4[512 + d];
    f2 xm = spl(xv[m]);
    hA += xm * (f2){w0.x, w0.y};  hB += xm * (f2){w0.z, w0.w};
    hC += xm * (f2){w1.x, w1.y};  hD += xm * (f2){w1.z, w1.w};
  }
  float h[8] = {hA.x, hA.y, hB.x, hB.y, hC.x, hC.y, hD.x, hD.y};
  const float H = fold8_allsum(h, lane);    // total h[jq]

  // ---------------- per-qubit (lane-parallel) tanh+LN+angle+u ----------------
  const float t0 = tstep[0];
  float tj;
  {
    float v = H + b_in[jq];
    v = fminf(15.f, fmaxf(-15.f, v));
    float e2 = __expf(2.f * v);
    tj = (e2 - 1.f) * __builtin_amdgcn_rcpf(e2 + 1.f);
  }
  const float mu = grp8_sum(tj) * 0.125f;
  const float dv = tj - mu;
  const float var = grp8_sum(dv * dv) * 0.125f;
  const float rstd = rsqrtf(var + 1e-5f);
  const float ang = dv * rstd * g[jq] + be[jq] + t0;

  {
    float sa, ca; __sincosf(ang * 0.5f, &sa, &ca);
    f2 v0 = spl(ca) * (f2){ca, -sa};
    f2 v1 = spl(sa) * (f2){sa, -ca};
    float s0, c0, s1, c1;
    __sincosf(qw[jq] * 0.5f, &s0, &c0);       // RX(q_weights[0,j])
    __sincosf(qw[9 + jq] * 0.5f, &s1, &c1);   // RZ(q_weights[1,j])
    f2 M00 = (f2){ c1 * c0, -s1 * c0};
    f2 M01 = (f2){-s1 * s0, -c1 * s0};
    f2 M10 = (f2){ s1 * s0, -c1 * s0};
    f2 M11 = (f2){ c1 * c0,  s1 * c0};
    f2 u0 = cmul(M00, v0) + cmul(M01, v1);
    f2 u1 = cmul(M10, v0) + cmul(M11, v1);
    if (lane < 8) {
      float4 uu = {u0.x, u0.y, u1.x, u1.y};
      *(float4*)&s_u[wv][jq][0] = uu;
    }
  }
  asm volatile("s_waitcnt lgkmcnt(0)" ::: "memory");
  __builtin_amdgcn_sched_barrier(0);

  // ---------------- build product state from u table ----------------
  f2 u0a[3], u1a[3];
#pragma unroll
  for (int i = 0; i < 3; ++i) {
    float4 uu = *(const float4*)&s_u[wv][i][0];
    u0a[i] = (f2){uu.x, uu.y};
    u1a[i] = (f2){uu.z, uu.w};
  }
  // lane wires: wire4@bit0, wire5@bit1, wire3@bit2, wire6@bit3, wire7@bit4
  f2 hl;
  {
    const f2* ub = (const f2*)&s_u[wv][0][0];   // [qubit][0]=u0, [qubit][1]=u1
    f2 r4 = ub[4 * 2 + ((lane >> 0) & 1)];
    f2 r5 = ub[5 * 2 + ((lane >> 1) & 1)];
    f2 r3 = ub[3 * 2 + ((lane >> 2) & 1)];
    f2 r6 = ub[6 * 2 + ((lane >> 3) & 1)];
    f2 r7 = ub[7 * 2 + ((lane >> 4) & 1)];
    hl = cmul(cmul(cmul(cmul(r4, r5), r3), r6), r7);
    if (lane & 32) hl = (f2){0.f, 0.f};         // ancilla |0>
  }
  f2 t01[4];
#pragma unroll
  for (int q = 0; q < 4; ++q)
    t01[q] = cmul((q & 1) ? u1a[0] : u0a[0], (q & 2) ? u1a[1] : u0a[1]);
  f2 st[8];
#pragma unroll
  for (int r = 0; r < 8; ++r)
    st[r] = cmul(cmul(t01[r & 3], (r & 4) ? u1a[2] : u0a[2]), hl);

  // ---------------- entangling layers ----------------
  Consts<PRE> cst{qw, ws};
  do_layer<PRE, true >(st, lane, cst, 1);
  do_layer<PRE, true >(st, lane, cst, 2);
  do_layer<PRE, false>(st, lane, cst, 3);   // last: skip C78/RY8/phase (exact)

  // ---------------- Z expectations ----------------
  float p[8];
#pragma unroll
  for (int r = 0; r < 8; ++r) p[r] = st[r].x * st[r].x + st[r].y * st[r].y;
  float tot = 0.f;
#pragma unroll
  for (int r = 0; r < 8; ++r) tot += p[r];

  float y[8];
  y[0] = (p[0] - p[1]) + (p[2] - p[3]) + (p[4] - p[5]) + (p[6] - p[7]);
  y[1] = (p[0] + p[1]) - (p[2] + p[3]) + (p[4] + p[5]) - (p[6] + p[7]);
  y[2] = (p[0] + p[1] + p[2] + p[3]) - (p[4] + p[5] + p[6] + p[7]);
  y[3] = (lane & 4)  ? -tot : tot;
  y[4] = (lane & 1)  ? -tot : tot;
  y[5] = (lane & 2)  ? -tot : tot;
  y[6] = (lane & 8)  ? -tot : tot;
  y[7] = (lane & 16) ? -tot : tot;
  const float Z = fold8_allsum(y, lane);    // z[jq]
  if (lane < 8) s_z[wv][jq] = Z;
  asm volatile("s_waitcnt lgkmcnt(0)" ::: "memory");
  __builtin_amdgcn_sched_barrier(0);

  float4 za = *(const float4*)&s_z[wv][0];
  float4 zb = *(const float4*)&s_z[wv][4];

  // ---------------- epilogue: out = x + z @ w_out^T + b_out ----------------
  const size_t base = (size_t)sample * ND;
  const float4* wo4 = (const float4*)w_out;   // [512][8]
  f2 z01 = (f2){za.x, za.y}, z23 = (f2){za.z, za.w};
  f2 z45 = (f2){zb.x, zb.y}, z67 = (f2){zb.z, zb.w};
#pragma unroll
  for (int m = 0; m < 8; ++m) {
    const int d = lane + 64 * m;
    float4 a  = wo4[2 * d];
    float4 b4 = wo4[2 * d + 1];
    f2 acc = z01 * (f2){a.x, a.y};
    acc += z23 * (f2){a.z, a.w};
    acc += z45 * (f2){b4.x, b4.y};
    acc += z67 * (f2){b4.z, b4.w};
    out[base + d] = xv[m] + b_out[d] + acc.x + acc.y;
  }
}

extern "C" void kernel_launch(void* const* d_in, const int* in_sizes, int n_in,
                              void* d_out, int out_size, void* d_ws, size_t ws_size,
                              hipStream_t stream) {
  const float* x     = (const float*)d_in[0];
  const float* ts    = (const float*)d_in[1];
  const float* w_in  = (const float*)d_in[2];
  const float* b_in  = (const float*)d_in[3];
  const float* g     = (const float*)d_in[4];
  const float* be    = (const float*)d_in[5];
  const float* qw    = (const float*)d_in[6];
  const float* w_out = (const float*)d_in[7];
  const float* b_out = (const float*)d_in[8];
  float* out = (float*)d_out;

  const bool pre = (d_ws != nullptr) && (ws_size >= 256);
  if (pre) {
    qpre_kernel<<<dim3(1), dim3(64), 0, stream>>>(qw, (float*)d_ws);
    qlayer_kernel<true><<<dim3(NSAMP / 4), dim3(256), 0, stream>>>(
        x, ts, w_in, b_in, g, be, qw, w_out, b_out, out, (const float*)d_ws);
  } else {
    qlayer_kernel<false><<<dim3(NSAMP / 4), dim3(256), 0, stream>>>(
        x, ts, w_in, b_in, g, be, qw, w_out, b_out, out, (const float*)d_ws);
  }
}

// Round 6
// 58.177 us; speedup vs baseline: 2.2769x; 1.0049x over previous
//
#include <hip/hip_runtime.h>
#include <math.h>

#define NSAMP 16384
#define ND    512

typedef float f2 __attribute__((ext_vector_type(2)));
__device__ __forceinline__ f2 spl(float x) { return (f2){x, x}; }

// ---------------- cross-lane primitives ----------------
template<int CTRL>
__device__ __forceinline__ float dppf(float x) {
  return __int_as_float(__builtin_amdgcn_update_dpp(
      __float_as_int(x), __float_as_int(x), CTRL, 0xF, 0xF, true));
}
template<int CTRL, int RM, int BM>
__device__ __forceinline__ float dppf_keep(float x) {
  return __int_as_float(__builtin_amdgcn_update_dpp(
      __float_as_int(x), __float_as_int(x), CTRL, RM, BM, false));
}
template<int P>
__device__ __forceinline__ float swzf(float x) {
  return __int_as_float(__builtin_amdgcn_ds_swizzle(__float_as_int(x), P));
}
__device__ __forceinline__ float bpermf(int addrB, float x) {
  return __int_as_float(__builtin_amdgcn_ds_bpermute(addrB, __float_as_int(x)));
}

#if __has_builtin(__builtin_amdgcn_permlane16_swap)
#define HAVE_PLSWAP 1
#endif
__device__ __forceinline__ void plswap16(float x, float& a, float& b) {
#ifdef HAVE_PLSWAP
  auto r = __builtin_amdgcn_permlane16_swap(__float_as_uint(x), __float_as_uint(x), false, false);
  a = __uint_as_float(r[0]); b = __uint_as_float(r[1]);
#else
  a = x; b = swzf<0x401F>(x);
#endif
}
__device__ __forceinline__ void plswap32(float x, float& a, float& b) {
#ifdef HAVE_PLSWAP
  auto r = __builtin_amdgcn_permlane32_swap(__float_as_uint(x), __float_as_uint(x), false, false);
  a = __uint_as_float(r[0]); b = __uint_as_float(r[1]);
#else
  a = x; b = __shfl_xor(x, 32, 64);
#endif
}

// butterfly exchange of an (re,im) pair: value of lane (lane ^ M)
template<int M>
__device__ __forceinline__ f2 bfly2(f2 x) {
  f2 r;
  if constexpr (M == 1)       { r.x = dppf<0xB1>(x.x);    r.y = dppf<0xB1>(x.y); }
  else if constexpr (M == 2)  { r.x = dppf<0x4E>(x.x);    r.y = dppf<0x4E>(x.y); }
  else if constexpr (M == 8)  { r.x = dppf<0x128>(x.x);   r.y = dppf<0x128>(x.y); }
  else if constexpr (M == 4)  { r.x = swzf<0x101F>(x.x);  r.y = swzf<0x101F>(x.y); }
  else if constexpr (M == 16) { r.x = swzf<0x401F>(x.x);  r.y = swzf<0x401F>(x.y); }
  else                        { r.x = __shfl_xor(x.x, 32, 64); r.y = __shfl_xor(x.y, 32, 64); }
  return r;
}

// sum over all 64 lanes of y[lane&7]; result on every lane (for its own j)
__device__ __forceinline__ float fold8_allsum(const float* y, int lane) {
  float v4[4];
#pragma unroll
  for (int i = 0; i < 4; ++i) {
    float keep = (lane & 1) ? y[2 * i + 1] : y[2 * i];
    float send = (lane & 1) ? y[2 * i]     : y[2 * i + 1];
    v4[i] = keep + dppf<0xB1>(send);
  }
  float v2[2];
#pragma unroll
  for (int i = 0; i < 2; ++i) {
    float keep = (lane & 2) ? v4[2 * i + 1] : v4[2 * i];
    float send = (lane & 2) ? v4[2 * i]     : v4[2 * i + 1];
    v2[i] = keep + dppf<0x4E>(send);
  }
  float keep = (lane & 4) ? v2[1] : v2[0];
  float send = (lane & 4) ? v2[0] : v2[1];
  float r = keep + swzf<0x101F>(send);
  r += dppf<0x128>(r);                          // xor8
  { float a, b; plswap16(r, a, b); r = a + b; } // +xor16
  { float a, b; plswap32(r, a, b); r = a + b; } // +xor32
  return r;
}

// all-reduce sum within each 8-lane group
__device__ __forceinline__ float grp8_sum(float x) {
  x += dppf<0xB1>(x);
  x += dppf<0x4E>(x);
  x += swzf<0x101F>(x);
  return x;
}

// complex multiply
__device__ __forceinline__ f2 cmul(f2 a, f2 b) {
  f2 bs = __builtin_shufflevector(b, b, 1, 0);
  f2 t  = (f2){-a.y, a.y} * bs;
  return spl(a.x) * b + t;
}

// ---------------- gates ----------------
template<int LB>
__device__ __forceinline__ void ry_local(f2* s, float c, float sv) {
#pragma unroll
  for (int r0 = 0; r0 < 8; ++r0) {
    if (r0 & (1 << LB)) continue;
    const int r1 = r0 | (1 << LB);
    f2 a0 = s[r0], a1 = s[r1];
    s[r0] = spl(c) * a0 - spl(sv) * a1;
    s[r1] = spl(sv) * a0 + spl(c) * a1;
  }
}
template<int LB>
__device__ __forceinline__ void rz_local(f2* s, f2 phm, f2 php) {
#pragma unroll
  for (int r = 0; r < 8; ++r) s[r] = cmul(s[r], (r & (1 << LB)) ? php : phm);
}
template<int M>
__device__ __forceinline__ void ry_lane(f2* s, float c, float se) {
#pragma unroll
  for (int r = 0; r < 8; ++r) {
    f2 p = bfly2<M>(s[r]);
    s[r] = spl(c) * s[r] + spl(se) * p;
  }
}
template<int CB, int TB>
__device__ __forceinline__ void cnot_ll(f2* s) {
#pragma unroll
  for (int r0 = 0; r0 < 8; ++r0) {
    if (!(r0 & (1 << CB)) || (r0 & (1 << TB))) continue;
    const int r1 = r0 | (1 << TB);
    f2 t = s[r0]; s[r0] = s[r1]; s[r1] = t;
  }
}
template<int CB, int TM>
__device__ __forceinline__ void cnot_lt(f2* s) {
#pragma unroll
  for (int r = 0; r < 8; ++r) {
    if (!(r & (1 << CB))) continue;
    s[r] = bfly2<TM>(s[r]);
  }
}
// lane-ctrl/lane-tgt CNOT as a fixed lane permutation: one bpermute per word
__device__ __forceinline__ void cnot_bperm(f2* s, int addrB) {
#pragma unroll
  for (int r = 0; r < 8; ++r) {
    s[r].x = bpermf(addrB, s[r].x);
    s[r].y = bpermf(addrB, s[r].y);
  }
}
// CNOT ctrl=m4 (banks 1,3), tgt=m1: masked quad_perm, others keep old
__device__ __forceinline__ void cnot_m4_t1(f2* s) {
#pragma unroll
  for (int r = 0; r < 8; ++r) {
    s[r].x = dppf_keep<0xB1, 0xF, 0xA>(s[r].x);
    s[r].y = dppf_keep<0xB1, 0xF, 0xA>(s[r].y);
  }
}
// CNOT ctrl=m1, tgt=m2: full quad_perm [0,3,2,1]
__device__ __forceinline__ void cnot_m1_t2(f2* s) {
#pragma unroll
  for (int r = 0; r < 8; ++r) {
    s[r].x = dppf<0x6C>(s[r].x);
    s[r].y = dppf<0x6C>(s[r].y);
  }
}
template<int TB>
__device__ __forceinline__ void cnot_tl(f2* s, bool cc) {
#pragma unroll
  for (int r0 = 0; r0 < 8; ++r0) {
    if (r0 & (1 << TB)) continue;
    const int r1 = r0 | (1 << TB);
    f2 n0, n1;
    n0.x = cc ? s[r1].x : s[r0].x;  n0.y = cc ? s[r1].y : s[r0].y;
    n1.x = cc ? s[r0].x : s[r1].x;  n1.y = cc ? s[r0].y : s[r1].y;
    s[r0] = n0; s[r1] = n1;
  }
}

// ---------------- prekernel: layer trig table ----------------
// ws[0..53]: (c,s) of qw[l*9+i]/2 for l=1..3, i=0..8  (f2 index (l-1)*9+i)
__global__ void qpre_kernel(const float* __restrict__ qw, float* __restrict__ ws) {
  int t = threadIdx.x;
  if (t < 27) {
    float s, c; __sincosf(qw[9 + t] * 0.5f, &s, &c);
    ws[2 * t] = c; ws[2 * t + 1] = s;
  }
}

template<bool PRE>
struct Consts {
  const float* qw; const float* ws;
  __device__ __forceinline__ f2 ltrig(int l, int i) const {
    if constexpr (PRE) {
      return ((const f2*)ws)[(l - 1) * 9 + i];
    } else {
      float s, c; __sincosf(qw[l * 9 + i] * 0.5f, &s, &c);
      return (f2){c, s};
    }
  }
};

// One entangling layer.
// MODE 1 (layer 1): mirrored ancilla "birth" (amp *= chi_{s7}[b5]) replaces
//   CNOT(7,8)+RY(8) exactly (ancilla was |0>, state mirrored across bit5);
//   then merged deferred phase.
// MODE 2 (layer 2): CNOT(7,8) via bpermute; RY(8) dropped (exact: wire 8 is
//   never touched afterwards -> unitary on traced-out subsystem); then phase.
// MODE 3 (layer 3): stop after RY(7) (C78/RY8/phase leave marginals invariant).
// Deferred RZs (wires 1..7) commute to layer end; Z0 stays inline.
template<bool PRE, int MODE>
__device__ __forceinline__ void do_layer(f2* st, int lane, const Consts<PRE>& cst, int l,
                                         int addr56, int addr67, int addr78) {
  f2 t[9];
#pragma unroll
  for (int i = 0; i < 9; ++i) t[i] = cst.ltrig(l, i);

  cnot_ll<0, 1>(st);                                       // CNOT(0,1)
  ry_local<0>(st, t[0].x, t[0].y);
  rz_local<0>(st, (f2){t[0].x, -t[0].y}, (f2){t[0].x, t[0].y});  // Z0 inline
  cnot_ll<1, 2>(st);                                       // CNOT(1,2)
  ry_local<1>(st, t[1].x, t[1].y);                         // Z1 deferred
  cnot_lt<2, 4>(st);                                       // CNOT(2,3)
  ry_local<2>(st, t[2].x, t[2].y);                         // Z2 deferred
  cnot_m4_t1(st);                                          // CNOT(3,4)
  { float se = (lane & 4) ? t[3].y : -t[3].y;
    ry_lane<4>(st, t[3].x, se); }                          // Z3 deferred
  cnot_m1_t2(st);                                          // CNOT(4,5)
  { float se = (lane & 1) ? t[4].y : -t[4].y;
    ry_lane<1>(st, t[4].x, se); }                          // Z4 deferred
  cnot_bperm(st, addr56);                                  // CNOT(5,6)
  { float se = (lane & 2) ? t[5].y : -t[5].y;
    ry_lane<2>(st, t[5].x, se); }                          // Z5 deferred
  cnot_bperm(st, addr67);                                  // CNOT(6,7)
  { float se = (lane & 8) ? t[6].y : -t[6].y;
    ry_lane<8>(st, t[6].x, se); }                          // Z6 deferred
  cnot_tl<0>(st, (lane & 16) != 0);                        // CNOT(7,0)
  { float se = (lane & 16) ? t[7].y : -t[7].y;
    ry_lane<16>(st, t[7].x, se); }                         // Z7 deferred

  if constexpr (MODE == 1) {
    // ancilla birth: chi0 = (c8,s8), chi1 = (-s8,c8); a = b5, s7 = m16
    const float wsel = (lane & 32) ? ((lane & 16) ? t[8].x : t[8].y)
                                   : ((lane & 16) ? -t[8].y : t[8].x);
#pragma unroll
    for (int r = 0; r < 8; ++r) st[r] = st[r] * spl(wsel);
  }
  if constexpr (MODE == 2) {
    cnot_bperm(st, addr78);                                // CNOT(7,8)
  }
  if constexpr (MODE != 3) {
    // merged deferred phase: local part (wires 1,2 on reg bits 1,2)
    f2 L4[4];
#pragma unroll
    for (int k = 0; k < 4; ++k) {
      f2 p1 = (f2){t[1].x, (k & 1) ? t[1].y : -t[1].y};
      f2 p2 = (f2){t[2].x, (k & 2) ? t[2].y : -t[2].y};
      L4[k] = cmul(p1, p2);
    }
    // lane part: wires 3..7 on masks {4,1,2,8,16}
    f2 phW = (f2){t[3].x, (lane & 4)  ? t[3].y : -t[3].y};
    phW = cmul(phW, (f2){t[4].x, (lane & 1)  ? t[4].y : -t[4].y});
    phW = cmul(phW, (f2){t[5].x, (lane & 2)  ? t[5].y : -t[5].y});
    phW = cmul(phW, (f2){t[6].x, (lane & 8)  ? t[6].y : -t[6].y});
    phW = cmul(phW, (f2){t[7].x, (lane & 16) ? t[7].y : -t[7].y});
    f2 pr[4];
#pragma unroll
    for (int k = 0; k < 4; ++k) pr[k] = cmul(L4[k], phW);
#pragma unroll
    for (int r = 0; r < 8; ++r) st[r] = cmul(st[r], pr[(r >> 1) & 3]);
  }
}

// Wire->lane-bit map (wires 0,1,2 = register bits 0,1,2):
//   wire4->m1, wire5->m2, wire3->m4, wire6->m8, wire7->m16, wire8(anc)->m32
template<bool PRE>
__global__ __launch_bounds__(256, 4) void qlayer_kernel(
    const float* __restrict__ x, const float* __restrict__ tstep,
    const float* __restrict__ w_in, const float* __restrict__ b_in,
    const float* __restrict__ g, const float* __restrict__ be,
    const float* __restrict__ qw, const float* __restrict__ w_out,
    const float* __restrict__ b_out, float* __restrict__ out,
    const float* __restrict__ ws)
{
  __shared__ __align__(16) float s_u[4][8][4];  // per-wave u table
  __shared__ __align__(16) float s_z[4][8];     // per-wave z table

  const int tid    = threadIdx.x;
  const int lane   = tid & 63;
  const int wv     = tid >> 6;
  const int sample = blockIdx.x * 4 + wv;
  const int jq     = lane & 7;              // this lane's owned qubit
  const int dbase  = lane << 3;             // this lane's 8 d-columns

  // CNOT lane-permutation addresses (bytes)
  const int addr56 = (lane ^ ((lane & 2) << 2)) << 2;
  const int addr67 = (lane ^ ((lane & 8) << 1)) << 2;
  const int addr78 = (lane ^ ((lane & 16) << 1)) << 2;

  // ---------------- input GEMM: h_j = sum_d x[d] * w_in[j][d] ----------------
  const float4* xr4 = (const float4*)(x + (size_t)sample * ND + dbase);
  const float4 xa = xr4[0], xb = xr4[1];
  const f2 xp0 = (f2){xa.x, xa.y}, xp1 = (f2){xa.z, xa.w};
  const f2 xp2 = (f2){xb.x, xb.y}, xp3 = (f2){xb.z, xb.w};

  float h[8];
#pragma unroll
  for (int j = 0; j < 8; ++j) {
    const float4* wj = (const float4*)(w_in + j * ND + dbase);
    float4 wa = wj[0], wb = wj[1];
    f2 acc = xp0 * (f2){wa.x, wa.y};
    acc += xp1 * (f2){wa.z, wa.w};
    acc += xp2 * (f2){wb.x, wb.y};
    acc += xp3 * (f2){wb.z, wb.w};
    h[j] = acc.x + acc.y;
  }
  const float H = fold8_allsum(h, lane);    // total h[jq]

  // ---------------- per-qubit (lane-parallel) tanh+LN+angle+u ----------------
  const float t0 = tstep[0];
  float tj;
  {
    float v = H + b_in[jq];
    v = fminf(15.f, fmaxf(-15.f, v));
    float e2 = __expf(2.f * v);
    tj = (e2 - 1.f) * __builtin_amdgcn_rcpf(e2 + 1.f);
  }
  const float mu = grp8_sum(tj) * 0.125f;
  const float dv = tj - mu;
  const float var = grp8_sum(dv * dv) * 0.125f;
  const float rstd = rsqrtf(var + 1e-5f);
  const float ang = dv * rstd * g[jq] + be[jq] + t0;

  {
    float sa, ca; __sincosf(ang * 0.5f, &sa, &ca);
    f2 v0 = spl(ca) * (f2){ca, -sa};
    f2 v1 = spl(sa) * (f2){sa, -ca};
    float s0, c0, s1, c1;
    __sincosf(qw[jq] * 0.5f, &s0, &c0);       // RX(q_weights[0,j])
    __sincosf(qw[9 + jq] * 0.5f, &s1, &c1);   // RZ(q_weights[1,j])
    f2 M00 = (f2){ c1 * c0, -s1 * c0};
    f2 M01 = (f2){-s1 * s0, -c1 * s0};
    f2 M10 = (f2){ s1 * s0, -c1 * s0};
    f2 M11 = (f2){ c1 * c0,  s1 * c0};
    f2 u0 = cmul(M00, v0) + cmul(M01, v1);
    f2 u1 = cmul(M10, v0) + cmul(M11, v1);
    if (lane < 8) {
      float4 uu = {u0.x, u0.y, u1.x, u1.y};
      *(float4*)&s_u[wv][jq][0] = uu;
    }
  }
  asm volatile("s_waitcnt lgkmcnt(0)" ::: "memory");
  __builtin_amdgcn_sched_barrier(0);

  // ---------------- build MIRRORED product state (bit5 spectator) ----------------
  f2 u0a[3], u1a[3];
#pragma unroll
  for (int i = 0; i < 3; ++i) {
    float4 uu = *(const float4*)&s_u[wv][i][0];
    u0a[i] = (f2){uu.x, uu.y};
    u1a[i] = (f2){uu.z, uu.w};
  }
  // lane wires: wire4@bit0, wire5@bit1, wire3@bit2, wire6@bit3, wire7@bit4
  f2 hl;
  {
    const f2* ub = (const f2*)&s_u[wv][0][0];   // [qubit][0]=u0, [qubit][1]=u1
    f2 r4 = ub[4 * 2 + ((lane >> 0) & 1)];
    f2 r5 = ub[5 * 2 + ((lane >> 1) & 1)];
    f2 r3 = ub[3 * 2 + ((lane >> 2) & 1)];
    f2 r6 = ub[6 * 2 + ((lane >> 3) & 1)];
    f2 r7 = ub[7 * 2 + ((lane >> 4) & 1)];
    hl = cmul(cmul(cmul(cmul(r4, r5), r3), r6), r7);
    // NOTE: no bit5 zeroing — state mirrored; ancilla handled by layer-1 birth
  }
  f2 t01[4];
#pragma unroll
  for (int q = 0; q < 4; ++q)
    t01[q] = cmul((q & 1) ? u1a[0] : u0a[0], (q & 2) ? u1a[1] : u0a[1]);
  f2 st[8];
#pragma unroll
  for (int r = 0; r < 8; ++r)
    st[r] = cmul(cmul(t01[r & 3], (r & 4) ? u1a[2] : u0a[2]), hl);

  // ---------------- entangling layers ----------------
  Consts<PRE> cst{qw, ws};
  do_layer<PRE, 1>(st, lane, cst, 1, addr56, addr67, addr78);
  do_layer<PRE, 2>(st, lane, cst, 2, addr56, addr67, addr78);
  do_layer<PRE, 3>(st, lane, cst, 3, addr56, addr67, addr78);

  // ---------------- Z expectations ----------------
  float p[8];
#pragma unroll
  for (int r = 0; r < 8; ++r) p[r] = st[r].x * st[r].x + st[r].y * st[r].y;
  float tot = 0.f;
#pragma unroll
  for (int r = 0; r < 8; ++r) tot += p[r];

  float y[8];
  y[0] = (p[0] - p[1]) + (p[2] - p[3]) + (p[4] - p[5]) + (p[6] - p[7]);
  y[1] = (p[0] + p[1]) - (p[2] + p[3]) + (p[4] + p[5]) - (p[6] + p[7]);
  y[2] = (p[0] + p[1] + p[2] + p[3]) - (p[4] + p[5] + p[6] + p[7]);
  y[3] = (lane & 4)  ? -tot : tot;
  y[4] = (lane & 1)  ? -tot : tot;
  y[5] = (lane & 2)  ? -tot : tot;
  y[6] = (lane & 8)  ? -tot : tot;
  y[7] = (lane & 16) ? -tot : tot;
  const float Z = fold8_allsum(y, lane);    // z[jq]
  if (lane < 8) s_z[wv][jq] = Z;
  asm volatile("s_waitcnt lgkmcnt(0)" ::: "memory");
  __builtin_amdgcn_sched_barrier(0);

  float4 za = *(const float4*)&s_z[wv][0];
  float4 zb = *(const float4*)&s_z[wv][4];

  // ---------------- epilogue: out = x + z @ w_out^T + b_out ----------------
  const f2 z01 = (f2){za.x, za.y}, z23 = (f2){za.z, za.w};
  const f2 z45 = (f2){zb.x, zb.y}, z67 = (f2){zb.z, zb.w};
  const float4* wo = (const float4*)(w_out + (size_t)dbase * 8);  // 8 rows x 32B, contiguous
  const float4* bo = (const float4*)(b_out + dbase);
  const float4 b0 = bo[0], b1 = bo[1];
  const float xk[8] = {xa.x, xa.y, xa.z, xa.w, xb.x, xb.y, xb.z, xb.w};
  const float bk[8] = {b0.x, b0.y, b0.z, b0.w, b1.x, b1.y, b1.z, b1.w};
  float o[8];
#pragma unroll
  for (int k = 0; k < 8; ++k) {
    float4 wa = wo[2 * k];
    float4 wb = wo[2 * k + 1];
    f2 acc = z01 * (f2){wa.x, wa.y};
    acc += z23 * (f2){wa.z, wa.w};
    acc += z45 * (f2){wb.x, wb.y};
    acc += z67 * (f2){wb.z, wb.w};
    o[k] = xk[k] + bk[k] + acc.x + acc.y;
  }
  float4* outp = (float4*)(out + (size_t)sample * ND + dbase);
  outp[0] = (float4){o[0], o[1], o[2], o[3]};
  outp[1] = (float4){o[4], o[5], o[6], o[7]};
}

extern "C" void kernel_launch(void* const* d_in, const int* in_sizes, int n_in,
                              void* d_out, int out_size, void* d_ws, size_t ws_size,
                              hipStream_t stream) {
  const float* x     = (const float*)d_in[0];
  const float* ts    = (const float*)d_in[1];
  const float* w_in  = (const float*)d_in[2];
  const float* b_in  = (const float*)d_in[3];
  const float* g     = (const float*)d_in[4];
  const float* be    = (const float*)d_in[5];
  const float* qw    = (const float*)d_in[6];
  const float* w_out = (const float*)d_in[7];
  const float* b_out = (const float*)d_in[8];
  float* out = (float*)d_out;

  const bool pre = (d_ws != nullptr) && (ws_size >= 256);
  if (pre) {
    qpre_kernel<<<dim3(1), dim3(64), 0, stream>>>(qw, (float*)d_ws);
    qlayer_kernel<true><<<dim3(NSAMP / 4), dim3(256), 0, stream>>>(
        x, ts, w_in, b_in, g, be, qw, w_out, b_out, out, (const float*)d_ws);
  } else {
    qlayer_kernel<false><<<dim3(NSAMP / 4), dim3(256), 0, stream>>>(
        x, ts, w_in, b_in, g, be, qw, w_out, b_out, out, (const float*)d_ws);
  }
}

// Round 7
// 56.455 us; speedup vs baseline: 2.3464x; 1.0305x over previous
//
#include <hip/hip_runtime.h>
#include <math.h>

#define NSAMP 16384
#define ND    512

typedef float f2 __attribute__((ext_vector_type(2)));
__device__ __forceinline__ f2 spl(float x) { return (f2){x, x}; }

// ---------------- cross-lane primitives ----------------
template<int CTRL>
__device__ __forceinline__ float dppf(float x) {
  return __int_as_float(__builtin_amdgcn_update_dpp(
      __float_as_int(x), __float_as_int(x), CTRL, 0xF, 0xF, true));
}
template<int CTRL, int RM, int BM>
__device__ __forceinline__ float dppf_keep(float x) {
  return __int_as_float(__builtin_amdgcn_update_dpp(
      __float_as_int(x), __float_as_int(x), CTRL, RM, BM, false));
}
template<int P>
__device__ __forceinline__ float swzf(float x) {
  return __int_as_float(__builtin_amdgcn_ds_swizzle(__float_as_int(x), P));
}
__device__ __forceinline__ float bpermf(int addrB, float x) {
  return __int_as_float(__builtin_amdgcn_ds_bpermute(addrB, __float_as_int(x)));
}

#if __has_builtin(__builtin_amdgcn_permlane16_swap)
#define HAVE_PLSWAP 1
#endif
__device__ __forceinline__ void plswap16(float x, float& a, float& b) {
#ifdef HAVE_PLSWAP
  auto r = __builtin_amdgcn_permlane16_swap(__float_as_uint(x), __float_as_uint(x), false, false);
  a = __uint_as_float(r[0]); b = __uint_as_float(r[1]);
#else
  a = x; b = swzf<0x401F>(x);
#endif
}
__device__ __forceinline__ void plswap32(float x, float& a, float& b) {
#ifdef HAVE_PLSWAP
  auto r = __builtin_amdgcn_permlane32_swap(__float_as_uint(x), __float_as_uint(x), false, false);
  a = __uint_as_float(r[0]); b = __uint_as_float(r[1]);
#else
  a = x; b = __shfl_xor(x, 32, 64);
#endif
}

// butterfly exchange of an (re,im) pair: value of lane (lane ^ M)
template<int M>
__device__ __forceinline__ f2 bfly2(f2 x) {
  f2 r;
  if constexpr (M == 1)       { r.x = dppf<0xB1>(x.x);    r.y = dppf<0xB1>(x.y); }
  else if constexpr (M == 2)  { r.x = dppf<0x4E>(x.x);    r.y = dppf<0x4E>(x.y); }
  else if constexpr (M == 8)  { r.x = dppf<0x128>(x.x);   r.y = dppf<0x128>(x.y); }
  else if constexpr (M == 4)  { r.x = swzf<0x101F>(x.x);  r.y = swzf<0x101F>(x.y); }
  else if constexpr (M == 16) { r.x = swzf<0x401F>(x.x);  r.y = swzf<0x401F>(x.y); }
  else                        { r.x = __shfl_xor(x.x, 32, 64); r.y = __shfl_xor(x.y, 32, 64); }
  return r;
}

// dual-sample interleaved: sum over all 64 lanes of y[lane&7]
__device__ __forceinline__ void fold8_allsum2(const float* yA, const float* yB,
                                              int lane, float& rA, float& rB) {
  float a4[4], b4[4];
#pragma unroll
  for (int i = 0; i < 4; ++i) {
    float kA = (lane & 1) ? yA[2 * i + 1] : yA[2 * i];
    float sA = (lane & 1) ? yA[2 * i]     : yA[2 * i + 1];
    float kB = (lane & 1) ? yB[2 * i + 1] : yB[2 * i];
    float sB = (lane & 1) ? yB[2 * i]     : yB[2 * i + 1];
    a4[i] = kA + dppf<0xB1>(sA);
    b4[i] = kB + dppf<0xB1>(sB);
  }
  float a2[2], b2[2];
#pragma unroll
  for (int i = 0; i < 2; ++i) {
    float kA = (lane & 2) ? a4[2 * i + 1] : a4[2 * i];
    float sA = (lane & 2) ? a4[2 * i]     : a4[2 * i + 1];
    float kB = (lane & 2) ? b4[2 * i + 1] : b4[2 * i];
    float sB = (lane & 2) ? b4[2 * i]     : b4[2 * i + 1];
    a2[i] = kA + dppf<0x4E>(sA);
    b2[i] = kB + dppf<0x4E>(sB);
  }
  float kA = (lane & 4) ? a2[1] : a2[0];
  float sA = (lane & 4) ? a2[0] : a2[1];
  float kB = (lane & 4) ? b2[1] : b2[0];
  float sB = (lane & 4) ? b2[0] : b2[1];
  rA = kA + swzf<0x101F>(sA);
  rB = kB + swzf<0x101F>(sB);
  rA += dppf<0x128>(rA);
  rB += dppf<0x128>(rB);
  { float a, b; plswap16(rA, a, b); rA = a + b; }
  { float a, b; plswap16(rB, a, b); rB = a + b; }
  { float a, b; plswap32(rA, a, b); rA = a + b; }
  { float a, b; plswap32(rB, a, b); rB = a + b; }
}

// all-reduce sum within each 8-lane group
__device__ __forceinline__ float grp8_sum(float x) {
  x += dppf<0xB1>(x);
  x += dppf<0x4E>(x);
  x += swzf<0x101F>(x);
  return x;
}

// complex multiply
__device__ __forceinline__ f2 cmul(f2 a, f2 b) {
  f2 bs = __builtin_shufflevector(b, b, 1, 0);
  f2 t  = (f2){-a.y, a.y} * bs;
  return spl(a.x) * b + t;
}

// ---------------- gates on dual state: s[16], sample = r>>3, wire bits = r&7 ----------------
template<int LB>
__device__ __forceinline__ void ry_local(f2* s, float c, float sv) {
#pragma unroll
  for (int r0 = 0; r0 < 16; ++r0) {
    if ((r0 & 7) & (1 << LB)) continue;
    const int r1 = r0 | (1 << LB);
    f2 a0 = s[r0], a1 = s[r1];
    s[r0] = spl(c) * a0 - spl(sv) * a1;
    s[r1] = spl(sv) * a0 + spl(c) * a1;
  }
}
template<int LB>
__device__ __forceinline__ void rz_local(f2* s, f2 phm, f2 php) {
#pragma unroll
  for (int r = 0; r < 16; ++r) s[r] = cmul(s[r], ((r & 7) & (1 << LB)) ? php : phm);
}
template<int M>
__device__ __forceinline__ void ry_lane(f2* s, float c, float se) {
#pragma unroll
  for (int r = 0; r < 16; ++r) {
    f2 p = bfly2<M>(s[r]);
    s[r] = spl(c) * s[r] + spl(se) * p;
  }
}
template<int CB, int TB>
__device__ __forceinline__ void cnot_ll(f2* s) {
#pragma unroll
  for (int r0 = 0; r0 < 16; ++r0) {
    if (!((r0 & 7) & (1 << CB)) || ((r0 & 7) & (1 << TB))) continue;
    const int r1 = r0 | (1 << TB);
    f2 t = s[r0]; s[r0] = s[r1]; s[r1] = t;
  }
}
template<int CB, int TM>
__device__ __forceinline__ void cnot_lt(f2* s) {
#pragma unroll
  for (int r = 0; r < 16; ++r) {
    if (!((r & 7) & (1 << CB))) continue;
    s[r] = bfly2<TM>(s[r]);
  }
}
__device__ __forceinline__ void cnot_bperm(f2* s, int addrB) {
#pragma unroll
  for (int r = 0; r < 16; ++r) {
    s[r].x = bpermf(addrB, s[r].x);
    s[r].y = bpermf(addrB, s[r].y);
  }
}
// CNOT ctrl=m4 (banks 1,3), tgt=m1: masked quad_perm, others keep old
__device__ __forceinline__ void cnot_m4_t1(f2* s) {
#pragma unroll
  for (int r = 0; r < 16; ++r) {
    s[r].x = dppf_keep<0xB1, 0xF, 0xA>(s[r].x);
    s[r].y = dppf_keep<0xB1, 0xF, 0xA>(s[r].y);
  }
}
// CNOT ctrl=m1, tgt=m2: full quad_perm [0,3,2,1]
__device__ __forceinline__ void cnot_m1_t2(f2* s) {
#pragma unroll
  for (int r = 0; r < 16; ++r) {
    s[r].x = dppf<0x6C>(s[r].x);
    s[r].y = dppf<0x6C>(s[r].y);
  }
}
template<int TB>
__device__ __forceinline__ void cnot_tl(f2* s, bool cc) {
#pragma unroll
  for (int r0 = 0; r0 < 16; ++r0) {
    if ((r0 & 7) & (1 << TB)) continue;
    const int r1 = r0 | (1 << TB);
    f2 n0, n1;
    n0.x = cc ? s[r1].x : s[r0].x;  n0.y = cc ? s[r1].y : s[r0].y;
    n1.x = cc ? s[r0].x : s[r1].x;  n1.y = cc ? s[r0].y : s[r1].y;
    s[r0] = n0; s[r1] = n1;
  }
}

// ---------------- prekernel: layer trig table ----------------
__global__ void qpre_kernel(const float* __restrict__ qw, float* __restrict__ ws) {
  int t = threadIdx.x;
  if (t < 27) {
    float s, c; __sincosf(qw[9 + t] * 0.5f, &s, &c);
    ws[2 * t] = c; ws[2 * t + 1] = s;
  }
}

template<bool PRE>
struct Consts {
  const float* qw; const float* ws;
  __device__ __forceinline__ f2 ltrig(int l, int i) const {
    if constexpr (PRE) {
      return ((const f2*)ws)[(l - 1) * 9 + i];
    } else {
      float s, c; __sincosf(qw[l * 9 + i] * 0.5f, &s, &c);
      return (f2){c, s};
    }
  }
};

// One entangling layer (dual-sample). MODE semantics as R5 (all exact):
// 1: ancilla birth scalar; 2: CNOT(7,8) bperm, RY(8) dropped; 3: truncated tail.
template<bool PRE, int MODE>
__device__ __forceinline__ void do_layer(f2* st, int lane, const Consts<PRE>& cst, int l,
                                         int addr56, int addr67, int addr78) {
  f2 t[9];
#pragma unroll
  for (int i = 0; i < 9; ++i) t[i] = cst.ltrig(l, i);

  cnot_ll<0, 1>(st);                                       // CNOT(0,1)
  ry_local<0>(st, t[0].x, t[0].y);
  rz_local<0>(st, (f2){t[0].x, -t[0].y}, (f2){t[0].x, t[0].y});  // Z0 inline
  cnot_ll<1, 2>(st);                                       // CNOT(1,2)
  ry_local<1>(st, t[1].x, t[1].y);                         // Z1 deferred
  cnot_lt<2, 4>(st);                                       // CNOT(2,3)
  ry_local<2>(st, t[2].x, t[2].y);                         // Z2 deferred
  cnot_m4_t1(st);                                          // CNOT(3,4)
  { float se = (lane & 4) ? t[3].y : -t[3].y;
    ry_lane<4>(st, t[3].x, se); }                          // Z3 deferred
  cnot_m1_t2(st);                                          // CNOT(4,5)
  { float se = (lane & 1) ? t[4].y : -t[4].y;
    ry_lane<1>(st, t[4].x, se); }                          // Z4 deferred
  cnot_bperm(st, addr56);                                  // CNOT(5,6)
  { float se = (lane & 2) ? t[5].y : -t[5].y;
    ry_lane<2>(st, t[5].x, se); }                          // Z5 deferred
  cnot_bperm(st, addr67);                                  // CNOT(6,7)
  { float se = (lane & 8) ? t[6].y : -t[6].y;
    ry_lane<8>(st, t[6].x, se); }                          // Z6 deferred
  cnot_tl<0>(st, (lane & 16) != 0);                        // CNOT(7,0)
  { float se = (lane & 16) ? t[7].y : -t[7].y;
    ry_lane<16>(st, t[7].x, se); }                         // Z7 deferred

  if constexpr (MODE == 1) {
    const float wsel = (lane & 32) ? ((lane & 16) ? t[8].x : t[8].y)
                                   : ((lane & 16) ? -t[8].y : t[8].x);
#pragma unroll
    for (int r = 0; r < 16; ++r) st[r] = st[r] * spl(wsel);
  }
  if constexpr (MODE == 2) {
    cnot_bperm(st, addr78);                                // CNOT(7,8)
  }
  if constexpr (MODE != 3) {
    // merged deferred phase (shared across both samples)
    f2 L4[4];
#pragma unroll
    for (int k = 0; k < 4; ++k) {
      f2 p1 = (f2){t[1].x, (k & 1) ? t[1].y : -t[1].y};
      f2 p2 = (f2){t[2].x, (k & 2) ? t[2].y : -t[2].y};
      L4[k] = cmul(p1, p2);
    }
    f2 phW = (f2){t[3].x, (lane & 4)  ? t[3].y : -t[3].y};
    phW = cmul(phW, (f2){t[4].x, (lane & 1)  ? t[4].y : -t[4].y});
    phW = cmul(phW, (f2){t[5].x, (lane & 2)  ? t[5].y : -t[5].y});
    phW = cmul(phW, (f2){t[6].x, (lane & 8)  ? t[6].y : -t[6].y});
    phW = cmul(phW, (f2){t[7].x, (lane & 16) ? t[7].y : -t[7].y});
    f2 pr[4];
#pragma unroll
    for (int k = 0; k < 4; ++k) pr[k] = cmul(L4[k], phW);
#pragma unroll
    for (int r = 0; r < 16; ++r) st[r] = cmul(st[r], pr[((r & 7) >> 1) & 3]);
  }
}

// Wire->lane-bit map (wires 0,1,2 = register bits 0,1,2):
//   wire4->m1, wire5->m2, wire3->m4, wire6->m8, wire7->m16, wire8(anc)->m32
template<bool PRE>
__global__ __launch_bounds__(256, 4) void qlayer_kernel(
    const float* __restrict__ x, const float* __restrict__ tstep,
    const float* __restrict__ w_in, const float* __restrict__ b_in,
    const float* __restrict__ g, const float* __restrict__ be,
    const float* __restrict__ qw, const float* __restrict__ w_out,
    const float* __restrict__ b_out, float* __restrict__ out,
    const float* __restrict__ ws)
{
  __shared__ __align__(16) float s_u[4][2][8][4];  // per-wave, per-sample u table
  __shared__ __align__(16) float s_z[4][2][8];     // per-wave, per-sample z table

  const int tid    = threadIdx.x;
  const int lane   = tid & 63;
  const int wv     = tid >> 6;
  const int smpA   = blockIdx.x * 8 + wv * 2;   // this wave's two samples
  const int smpB   = smpA + 1;
  const int jq     = lane & 7;
  const int dbase  = lane << 3;

  const int addr56 = (lane ^ ((lane & 2) << 2)) << 2;
  const int addr67 = (lane ^ ((lane & 8) << 1)) << 2;
  const int addr78 = (lane ^ ((lane & 16) << 1)) << 2;

  // ---------------- input GEMM (w_in loads shared by both samples) ----------------
  const float4* xrA = (const float4*)(x + (size_t)smpA * ND + dbase);
  const float4* xrB = (const float4*)(x + (size_t)smpB * ND + dbase);
  const float4 xaA = xrA[0], xbA = xrA[1];
  const float4 xaB = xrB[0], xbB = xrB[1];
  const f2 a0 = (f2){xaA.x, xaA.y}, a1 = (f2){xaA.z, xaA.w};
  const f2 a2 = (f2){xbA.x, xbA.y}, a3 = (f2){xbA.z, xbA.w};
  const f2 b0 = (f2){xaB.x, xaB.y}, b1 = (f2){xaB.z, xaB.w};
  const f2 b2 = (f2){xbB.x, xbB.y}, b3 = (f2){xbB.z, xbB.w};

  float hA[8], hB[8];
#pragma unroll
  for (int j = 0; j < 8; ++j) {
    const float4* wj = (const float4*)(w_in + j * ND + dbase);
    float4 wa = wj[0], wb = wj[1];
    f2 w0 = (f2){wa.x, wa.y}, w1 = (f2){wa.z, wa.w};
    f2 w2 = (f2){wb.x, wb.y}, w3 = (f2){wb.z, wb.w};
    f2 accA = a0 * w0 + a1 * w1 + a2 * w2 + a3 * w3;
    f2 accB = b0 * w0 + b1 * w1 + b2 * w2 + b3 * w3;
    hA[j] = accA.x + accA.y;
    hB[j] = accB.x + accB.y;
  }
  float HA, HB;
  fold8_allsum2(hA, hB, lane, HA, HB);

  // ---------------- per-qubit tanh+LN+angle (dual) ----------------
  const float t0  = tstep[0];
  const float bj  = b_in[jq];
  const float gj  = g[jq];
  const float bej = be[jq];
  float tjA, tjB;
  {
    float vA = fminf(15.f, fmaxf(-15.f, HA + bj));
    float vB = fminf(15.f, fmaxf(-15.f, HB + bj));
    float eA = __expf(2.f * vA), eB = __expf(2.f * vB);
    tjA = (eA - 1.f) * __builtin_amdgcn_rcpf(eA + 1.f);
    tjB = (eB - 1.f) * __builtin_amdgcn_rcpf(eB + 1.f);
  }
  const float muA = grp8_sum(tjA) * 0.125f;
  const float muB = grp8_sum(tjB) * 0.125f;
  const float dvA = tjA - muA, dvB = tjB - muB;
  const float varA = grp8_sum(dvA * dvA) * 0.125f;
  const float varB = grp8_sum(dvB * dvB) * 0.125f;
  const float angA = dvA * rsqrtf(varA + 1e-5f) * gj + bej + t0;
  const float angB = dvB * rsqrtf(varB + 1e-5f) * gj + bej + t0;

  // ---------------- u vectors (M shared across samples) ----------------
  {
    float s0, c0, s1, c1;
    __sincosf(qw[jq] * 0.5f, &s0, &c0);
    __sincosf(qw[9 + jq] * 0.5f, &s1, &c1);
    f2 M00 = (f2){ c1 * c0, -s1 * c0};
    f2 M01 = (f2){-s1 * s0, -c1 * s0};
    f2 M10 = (f2){ s1 * s0, -c1 * s0};
    f2 M11 = (f2){ c1 * c0,  s1 * c0};
    float saA, caA; __sincosf(angA * 0.5f, &saA, &caA);
    float saB, caB; __sincosf(angB * 0.5f, &saB, &caB);
    f2 v0A = spl(caA) * (f2){caA, -saA};
    f2 v1A = spl(saA) * (f2){saA, -caA};
    f2 v0B = spl(caB) * (f2){caB, -saB};
    f2 v1B = spl(saB) * (f2){saB, -caB};
    f2 u0A = cmul(M00, v0A) + cmul(M01, v1A);
    f2 u1A = cmul(M10, v0A) + cmul(M11, v1A);
    f2 u0B = cmul(M00, v0B) + cmul(M01, v1B);
    f2 u1B = cmul(M10, v0B) + cmul(M11, v1B);
    if (lane < 16) {
      const int sb = lane >> 3;          // 0: sample A, 1: sample B
      f2 u0 = sb ? u0B : u0A;
      f2 u1 = sb ? u1B : u1A;
      *(float4*)&s_u[wv][sb][jq][0] = (float4){u0.x, u0.y, u1.x, u1.y};
    }
  }
  asm volatile("s_waitcnt lgkmcnt(0)" ::: "memory");
  __builtin_amdgcn_sched_barrier(0);

  // ---------------- build MIRRORED product states ----------------
  f2 st[16];
#pragma unroll
  for (int smp = 0; smp < 2; ++smp) {
    const f2* ub = (const f2*)&s_u[wv][smp][0][0];
    f2 r4 = ub[4 * 2 + ((lane >> 0) & 1)];
    f2 r5 = ub[5 * 2 + ((lane >> 1) & 1)];
    f2 r3 = ub[3 * 2 + ((lane >> 2) & 1)];
    f2 r6 = ub[6 * 2 + ((lane >> 3) & 1)];
    f2 r7 = ub[7 * 2 + ((lane >> 4) & 1)];
    f2 hl = cmul(cmul(cmul(cmul(r4, r5), r3), r6), r7);
    f2 u0q0 = ub[0], u1q0 = ub[1], u0q1 = ub[2], u1q1 = ub[3];
    f2 u0q2 = ub[4], u1q2 = ub[5];
    f2 t01[4];
#pragma unroll
    for (int q = 0; q < 4; ++q)
      t01[q] = cmul((q & 1) ? u1q0 : u0q0, (q & 2) ? u1q1 : u0q1);
#pragma unroll
    for (int r = 0; r < 8; ++r)
      st[smp * 8 + r] = cmul(cmul(t01[r & 3], (r & 4) ? u1q2 : u0q2), hl);
  }

  // ---------------- entangling layers ----------------
  Consts<PRE> cst{qw, ws};
  do_layer<PRE, 1>(st, lane, cst, 1, addr56, addr67, addr78);
  do_layer<PRE, 2>(st, lane, cst, 2, addr56, addr67, addr78);
  do_layer<PRE, 3>(st, lane, cst, 3, addr56, addr67, addr78);

  // ---------------- Z expectations (dual) ----------------
  float pA[8], pB[8];
#pragma unroll
  for (int r = 0; r < 8; ++r) {
    pA[r] = st[r].x * st[r].x + st[r].y * st[r].y;
    pB[r] = st[8 + r].x * st[8 + r].x + st[8 + r].y * st[8 + r].y;
  }
  float totA = 0.f, totB = 0.f;
#pragma unroll
  for (int r = 0; r < 8; ++r) { totA += pA[r]; totB += pB[r]; }

  float yA[8], yB[8];
  yA[0] = (pA[0] - pA[1]) + (pA[2] - pA[3]) + (pA[4] - pA[5]) + (pA[6] - pA[7]);
  yB[0] = (pB[0] - pB[1]) + (pB[2] - pB[3]) + (pB[4] - pB[5]) + (pB[6] - pB[7]);
  yA[1] = (pA[0] + pA[1]) - (pA[2] + pA[3]) + (pA[4] + pA[5]) - (pA[6] + pA[7]);
  yB[1] = (pB[0] + pB[1]) - (pB[2] + pB[3]) + (pB[4] + pB[5]) - (pB[6] + pB[7]);
  yA[2] = (pA[0] + pA[1] + pA[2] + pA[3]) - (pA[4] + pA[5] + pA[6] + pA[7]);
  yB[2] = (pB[0] + pB[1] + pB[2] + pB[3]) - (pB[4] + pB[5] + pB[6] + pB[7]);
  yA[3] = (lane & 4)  ? -totA : totA;  yB[3] = (lane & 4)  ? -totB : totB;
  yA[4] = (lane & 1)  ? -totA : totA;  yB[4] = (lane & 1)  ? -totB : totB;
  yA[5] = (lane & 2)  ? -totA : totA;  yB[5] = (lane & 2)  ? -totB : totB;
  yA[6] = (lane & 8)  ? -totA : totA;  yB[6] = (lane & 8)  ? -totB : totB;
  yA[7] = (lane & 16) ? -totA : totA;  yB[7] = (lane & 16) ? -totB : totB;
  float ZA, ZB;
  fold8_allsum2(yA, yB, lane, ZA, ZB);
  if (lane < 16) {
    const int sb = lane >> 3;
    s_z[wv][sb][jq] = sb ? ZB : ZA;
  }
  asm volatile("s_waitcnt lgkmcnt(0)" ::: "memory");
  __builtin_amdgcn_sched_barrier(0);

  const float4 zaA = *(const float4*)&s_z[wv][0][0];
  const float4 zbA = *(const float4*)&s_z[wv][0][4];
  const float4 zaB = *(const float4*)&s_z[wv][1][0];
  const float4 zbB = *(const float4*)&s_z[wv][1][4];

  // ---------------- epilogue (w_out/b_out loads shared) ----------------
  const f2 zA01 = (f2){zaA.x, zaA.y}, zA23 = (f2){zaA.z, zaA.w};
  const f2 zA45 = (f2){zbA.x, zbA.y}, zA67 = (f2){zbA.z, zbA.w};
  const f2 zB01 = (f2){zaB.x, zaB.y}, zB23 = (f2){zaB.z, zaB.w};
  const f2 zB45 = (f2){zbB.x, zbB.y}, zB67 = (f2){zbB.z, zbB.w};
  const float4* wo = (const float4*)(w_out + (size_t)dbase * 8);
  const float4* bo = (const float4*)(b_out + dbase);
  const float4 bo0 = bo[0], bo1 = bo[1];
  const float xkA[8] = {xaA.x, xaA.y, xaA.z, xaA.w, xbA.x, xbA.y, xbA.z, xbA.w};
  const float xkB[8] = {xaB.x, xaB.y, xaB.z, xaB.w, xbB.x, xbB.y, xbB.z, xbB.w};
  const float bk[8]  = {bo0.x, bo0.y, bo0.z, bo0.w, bo1.x, bo1.y, bo1.z, bo1.w};
  float oA[8], oB[8];
#pragma unroll
  for (int k = 0; k < 8; ++k) {
    float4 wa = wo[2 * k];
    float4 wb = wo[2 * k + 1];
    f2 w01 = (f2){wa.x, wa.y}, w23 = (f2){wa.z, wa.w};
    f2 w45 = (f2){wb.x, wb.y}, w67 = (f2){wb.z, wb.w};
    f2 accA = zA01 * w01 + zA23 * w23 + zA45 * w45 + zA67 * w67;
    f2 accB = zB01 * w01 + zB23 * w23 + zB45 * w45 + zB67 * w67;
    oA[k] = xkA[k] + bk[k] + accA.x + accA.y;
    oB[k] = xkB[k] + bk[k] + accB.x + accB.y;
  }
  float4* outA = (float4*)(out + (size_t)smpA * ND + dbase);
  float4* outB = (float4*)(out + (size_t)smpB * ND + dbase);
  outA[0] = (float4){oA[0], oA[1], oA[2], oA[3]};
  outA[1] = (float4){oA[4], oA[5], oA[6], oA[7]};
  outB[0] = (float4){oB[0], oB[1], oB[2], oB[3]};
  outB[1] = (float4){oB[4], oB[5], oB[6], oB[7]};
}

extern "C" void kernel_launch(void* const* d_in, const int* in_sizes, int n_in,
                              void* d_out, int out_size, void* d_ws, size_t ws_size,
                              hipStream_t stream) {
  const float* x     = (const float*)d_in[0];
  const float* ts    = (const float*)d_in[1];
  const float* w_in  = (const float*)d_in[2];
  const float* b_in  = (const float*)d_in[3];
  const float* g     = (const float*)d_in[4];
  const float* be    = (const float*)d_in[5];
  const float* qw    = (const float*)d_in[6];
  const float* w_out = (const float*)d_in[7];
  const float* b_out = (const float*)d_in[8];
  float* out = (float*)d_out;

  const bool pre = (d_ws != nullptr) && (ws_size >= 256);
  if (pre) {
    qpre_kernel<<<dim3(1), dim3(64), 0, stream>>>(qw, (float*)d_ws);
    qlayer_kernel<true><<<dim3(NSAMP / 8), dim3(256), 0, stream>>>(
        x, ts, w_in, b_in, g, be, qw, w_out, b_out, out, (const float*)d_ws);
  } else {
    qlayer_kernel<false><<<dim3(NSAMP / 8), dim3(256), 0, stream>>>(
        x, ts, w_in, b_in, g, be, qw, w_out, b_out, out, (const float*)d_ws);
  }
}